// Round 5
// baseline (3659.322 us; speedup 1.0000x reference)
//
#include <hip/hip_runtime.h>

// Kalman filter, B=256 T=512 S=64 M=32.
// Kernel 1 (1 WG, 1024 thr): batch-independent Riccati recursion, converged
// Newton-Schulz inverse with REACHABLE tolerance + iteration caps (cost-
// bounded; correctness insensitive to cap since Y keeps refining each iter).
// Runs exactly T_EXACT=192 steps (beyond: gain drift ~rho^2t ~ 1e-8), then
// emits closed-loop A = F(I-KH), G = FK. Writes K^T[t] ([64][32]) per step.
// Kernel 2 (32 blocks x 512 thr, one wave per batch, 8 waves/block = 2/SIMD
// for latency overlap): linear state recursion. t<T_EXACT: exact K_t
// (coalesced 128B/lane rows) + per-wave f4 LDS broadcasts. t>=T_EXACT:
// x <- A x + G o with A,G,H rows in VGPRs.

#define Sdim 64
#define Mdim 32
#define Tdim 512
#define T_EXACT 192

#define NEWTON_TOL 4e-4f

typedef float f4 __attribute__((ext_vector_type(4)));

// ---------------------------------------------------------------------------
// Kernel 1: Riccati recursion (single workgroup, 1024 threads)
// ---------------------------------------------------------------------------
__global__ __launch_bounds__(1024)
void riccati_kernel(const float* __restrict__ F, const float* __restrict__ H,
                    const float* __restrict__ Q, const float* __restrict__ R,
                    const float* __restrict__ P0,
                    float* __restrict__ K_T,      // [T_EXACT][64][32] f32
                    float* __restrict__ AT_g,     // [16][64] f4 (A[l][4j..] at [j][l])
                    float* __restrict__ GT_g)     // [8][64]  f4
{
    __shared__ __align__(16) float Ps [64*64];
    __shared__ __align__(16) float Gs [64*68];     // stride-68 scratch (also FK @33)
    __shared__ __align__(16) float HPs[32*64];
    __shared__ __align__(16) float Hs [32*65+4];
    __shared__ __align__(16) float Fs [64*65+4];
    __shared__ __align__(16) float FTs[64*64];
    __shared__ __align__(16) float Sms[32*33+4];
    __shared__ __align__(16) float Ys [32*33+4];
    __shared__ __align__(16) float T1s[32*33+4];
    __shared__ __align__(16) float Yns[32*33+4];
    __shared__ __align__(16) float KpT[64*33+4];   // K'^T: KpT[s*33+m] = K'[m][s]
    __shared__ int red_a, restarted;

    const int tid = threadIdx.x;
    f4* Ps4  = (f4*)Ps;
    f4* Gs4  = (f4*)Gs;
    f4* HP4  = (f4*)HPs;
    f4* FT4  = (f4*)FTs;
    f4* KT_g4 = (f4*)K_T;
    f4* AT_g4 = (f4*)AT_g;
    f4* GT_g4 = (f4*)GT_g;
    const f4* Q4 = (const f4*)Q;

    for (int i = tid; i < 64*64; i += 1024) {
        int r = i >> 6, c = i & 63;
        float v = F[i];
        Fs[r*65 + c] = v;
        FTs[c*64 + r] = v;      // FT[k][l] = F[l][k]
        Ps[i] = P0[i];
    }
    for (int i = tid; i < 32*64; i += 1024) {
        int mm = i >> 6, c = i & 63;
        Hs[mm*65 + c] = H[i];
    }
    __syncthreads();

    const int r16 = tid >> 4, j16 = tid & 15;   // [64 rows x 16 f4-cols]
    const int i32 = tid >> 5, j32 = tid & 31;   // [32 x 32]

    { // initial predict: Ps = F P0 F^T + Q
        f4 acc = {0.f,0.f,0.f,0.f};
        #pragma unroll 8
        for (int k = 0; k < 64; ++k) acc += Fs[r16*65 + k] * Ps4[k*16 + j16];
        Gs4[r16*17 + j16] = acc;
    }
    __syncthreads();
    {
        f4 acc = Q4[r16*16 + j16];
        #pragma unroll 8
        for (int k = 0; k < 64; ++k) acc += Gs[r16*68 + k] * FT4[k*16 + j16];
        Ps4[r16*16 + j16] = acc;
    }
    __syncthreads();

    float* Ycur = Ys;
    float* Yalt = Yns;

    for (int t = 0; t < T_EXACT; ++t) {
        if (tid < 512) {                        // a: HP = H * P
            int mm = tid >> 4, j = tid & 15;
            f4 acc = {0.f,0.f,0.f,0.f};
            #pragma unroll 8
            for (int k = 0; k < 64; ++k) acc += Hs[mm*65 + k] * Ps4[k*16 + j];
            HP4[mm*16 + j] = acc;
        }
        __syncthreads();
        {                                       // b: Sm = HP H^T + R
            float acc = R[i32*32 + j32];
            #pragma unroll 8
            for (int s = 0; s < 64; ++s) acc += HPs[i32*64 + s] * Hs[j32*65 + s];
            Sms[i32*33 + j32] = acc;
            if (tid == 0) { red_a = 0; restarted = 0; }
        }
        __syncthreads();

        if (t == 0) {                           // Newton init: Y = I / maxrowsum
            if (tid < 32) {
                float rs = 0.f;
                for (int jj = 0; jj < 32; ++jj) rs += fabsf(Sms[tid*33 + jj]);
                atomicMax(&red_a, __float_as_int(rs));
            }
            __syncthreads();
            float inv = 1.0f / __int_as_float(red_a);
            Ycur[i32*33 + j32] = (i32 == j32) ? inv : 0.f;
            if (tid == 0) red_a = 0;
            __syncthreads();
        }

        // --- Newton-Schulz: refine Y ~= Sm^{-1}. Check-first with wave-level
        // max-reduce (16 atomics, not 1024). Iteration caps bound COST only:
        // if TOL is unreachable, Y still refines every iteration.
        const int cap = (t == 0) ? 40 : (t <= 8 ? 24 : 8);
        for (int it = 0; it < cap; ++it) {
            float acc = 0.f;
            #pragma unroll 8
            for (int k = 0; k < 32; ++k) acc += Sms[i32*33 + k] * Ycur[k*33 + j32];
            T1s[i32*33 + j32] = acc;
            float e = fabsf(((i32 == j32) ? 1.f : 0.f) - acc);
            #pragma unroll
            for (int off = 32; off; off >>= 1) e = fmaxf(e, __shfl_xor(e, off, 64));
            if ((tid & 63) == 0) atomicMax(&red_a, __float_as_int(e));
            __syncthreads();
            float resid = __int_as_float(red_a);        // uniform
            if (resid < NEWTON_TOL) break;
            bool bad = !(resid < 1e30f);
            if ((bad || resid > 0.9f) && restarted == 0) {
                // rescue: fresh re-init from current Sm (divergence guard)
                if (tid == 0) red_a = 0;
                __syncthreads();
                if (tid < 32) {
                    float rs = 0.f;
                    for (int jj = 0; jj < 32; ++jj) rs += fabsf(Sms[tid*33 + jj]);
                    atomicMax(&red_a, __float_as_int(rs));
                }
                __syncthreads();
                float inv = 1.0f / __int_as_float(red_a);
                Ycur[i32*33 + j32] = (i32 == j32) ? inv : 0.f;
                if (tid == 0) { restarted = 1; red_a = 0; }
                __syncthreads();
                continue;
            }
            float up = 2.f * Ycur[i32*33 + j32];
            #pragma unroll 8
            for (int k = 0; k < 32; ++k) up -= Ycur[i32*33 + k] * T1s[k*33 + j32];
            Yalt[i32*33 + j32] = up;
            if (tid == 0) red_a = 0;
            __syncthreads();
            float* tmp = Ycur; Ycur = Yalt; Yalt = tmp;
        }

        if (tid < 512) {                        // d: K' = Y * HP -> KpT
            int mm = tid >> 4, j = tid & 15;
            f4 acc = {0.f,0.f,0.f,0.f};
            #pragma unroll 8
            for (int n = 0; n < 32; ++n) acc += Ycur[mm*33 + n] * HP4[n*16 + j];
            int s0 = j * 4;
            KpT[(s0    )*33 + mm] = acc[0];
            KpT[(s0 + 1)*33 + mm] = acc[1];
            KpT[(s0 + 2)*33 + mm] = acc[2];
            KpT[(s0 + 3)*33 + mm] = acc[3];
        }
        __syncthreads();

        if (tid < 512) {                        // store K^T[t] coalesced (f4)
            int s = tid >> 3, m4 = tid & 7;
            f4 v = { KpT[s*33 + m4*4 + 0], KpT[s*33 + m4*4 + 1],
                     KpT[s*33 + m4*4 + 2], KpT[s*33 + m4*4 + 3] };
            KT_g4[(size_t)t*512 + tid] = v;
        }

        if (t == T_EXACT - 1) {                 // emit closed-loop A, G
            // FK[l][m] = sum_s F[l][s] K'[m][s] -> Gs stride 33
            for (int i = tid; i < 64*32; i += 1024) {
                int l = i >> 5, mm = i & 31;
                float acc = 0.f;
                #pragma unroll 8
                for (int s = 0; s < 64; ++s) acc += Fs[l*65 + s] * KpT[s*33 + mm];
                Gs[l*33 + mm] = acc;
            }
            __syncthreads();
            {   // A = F - FK*H; AT_g4[j4*64 + l] = {A[l][4j4+c]}
                int l = tid & 63, j4 = tid >> 6;
                f4 aa;
                #pragma unroll
                for (int c = 0; c < 4; ++c) {
                    int j = j4*4 + c;
                    float a = Fs[l*65 + j];
                    #pragma unroll 8
                    for (int mm = 0; mm < 32; ++mm) a -= Gs[l*33 + mm] * Hs[mm*65 + j];
                    aa[c] = a;
                }
                AT_g4[j4*64 + l] = aa;
            }
            if (tid < 512) {                    // G = FK; GT_g4[m4*64 + l]
                int l = tid & 63, m4 = tid >> 6;
                f4 gg = { Gs[l*33 + m4*4 + 0], Gs[l*33 + m4*4 + 1],
                          Gs[l*33 + m4*4 + 2], Gs[l*33 + m4*4 + 3] };
                GT_g4[m4*64 + l] = gg;
            }
            break;
        }

        {                                       // e: P -= K'^T * HP (own element)
            f4 acc = Ps4[r16*16 + j16];
            #pragma unroll 8
            for (int mm = 0; mm < 32; ++mm) acc -= KpT[r16*33 + mm] * HP4[mm*16 + j16];
            Ps4[r16*16 + j16] = acc;
        }
        __syncthreads();
        {                                       // f: G = F * P_upd
            f4 acc = {0.f,0.f,0.f,0.f};
            #pragma unroll 8
            for (int k = 0; k < 64; ++k) acc += Fs[r16*65 + k] * Ps4[k*16 + j16];
            Gs4[r16*17 + j16] = acc;
        }
        __syncthreads();
        {                                       // g: P = G F^T + Q
            f4 acc = Q4[r16*16 + j16];
            #pragma unroll 8
            for (int k = 0; k < 64; ++k) acc += Gs[r16*68 + k] * FT4[k*16 + j16];
            Ps4[r16*16 + j16] = acc;
        }
        __syncthreads();
    }
}

// ---------------------------------------------------------------------------
// Kernel 2: per-batch state recursion. 32 blocks x 512 thr = 8 waves/block
// (2 waves/SIMD -> LDS-latency chains overlap). One wave per batch; per-wave
// private LDS slices; no block barriers (per-wave s_waitcnt only).
// ---------------------------------------------------------------------------
__global__ __launch_bounds__(512, 2)
void filter_kernel(const float* __restrict__ obs, const float* __restrict__ F,
                   const float* __restrict__ H, const float* __restrict__ x0,
                   const float* __restrict__ K_T, const float* __restrict__ AT_g,
                   const float* __restrict__ GT_g, float* __restrict__ out)
{
    const int lane = threadIdx.x & 63;
    const int wv   = threadIdx.x >> 6;
    const int b    = blockIdx.x * 8 + wv;
    const int m    = lane & 31;

    __shared__ __align__(16) float xb[8][64];
    __shared__ __align__(16) float rb[8][32];
    __shared__ __align__(16) float ub[8][64];
    float* xbw = xb[wv];
    float* rbw = rb[wv];
    float* ubw = ub[wv];
    const f4* xb4 = (const f4*)xbw;
    const f4* rb4 = (const f4*)rbw;
    const f4* ub4 = (const f4*)ubw;

    f4 Fr4[16], Hr4[16];
    #pragma unroll
    for (int k = 0; k < 16; ++k) Fr4[k] = ((const f4*)(F + lane*64))[k];
    #pragma unroll
    for (int k = 0; k < 16; ++k) Hr4[k] = ((const f4*)(H + m*64))[k];

    float x;
    {   // x = F x0 (initial predict)
        f4 a = {0.f,0.f,0.f,0.f};
        #pragma unroll
        for (int k = 0; k < 16; ++k) a += Fr4[k] * ((const f4*)x0)[k];
        x = (a[0]+a[1]) + (a[2]+a[3]);
    }

    const float* obs_b = obs + (size_t)b * (Tdim*Mdim);
    float*       out_b = out + (size_t)b * (Tdim*Mdim);
    float o0 = obs_b[m];
    float o1 = obs_b[Mdim + m];

    const f4* KT4 = (const f4*)K_T;

    // ---- exact phase: t in [0, T_EXACT)
    for (int t = 0; t < T_EXACT; ++t) {
        f4 ku[8];                               // lane's K^T row (128B coalesced)
        #pragma unroll
        for (int k = 0; k < 8; ++k) ku[k] = KT4[(size_t)t*512 + lane*8 + k];

        xbw[lane] = x;
        asm volatile("s_waitcnt lgkmcnt(0)" ::: "memory");
        f4 za = {0.f,0.f,0.f,0.f};
        #pragma unroll
        for (int k = 0; k < 16; ++k) za += Hr4[k] * xb4[k];
        float z = (za[0]+za[1]) + (za[2]+za[3]);
        if (lane < 32) { out_b[t*Mdim + lane] = z; rbw[lane] = o0 - z; }
        o0 = o1;
        if (t + 2 < Tdim) o1 = obs_b[(t+2)*Mdim + m];
        asm volatile("s_waitcnt lgkmcnt(0)" ::: "memory");
        f4 ua = {0.f,0.f,0.f,0.f};
        #pragma unroll
        for (int k = 0; k < 8; ++k) ua += ku[k] * rb4[k];
        float u = x + (ua[0]+ua[1]) + (ua[2]+ua[3]);
        ubw[lane] = u;
        asm volatile("s_waitcnt lgkmcnt(0)" ::: "memory");
        f4 xa = {0.f,0.f,0.f,0.f};
        #pragma unroll
        for (int k = 0; k < 16; ++k) xa += Fr4[k] * ub4[k];
        x = (xa[0]+xa[1]) + (xa[2]+xa[3]);
    }

    // ---- frozen phase: x <- A x + G o, A/G rows in VGPRs
    {
        f4 Ar[16], Gr[8];
        #pragma unroll
        for (int k = 0; k < 16; ++k) Ar[k] = ((const f4*)AT_g)[k*64 + lane];
        #pragma unroll
        for (int k = 0; k < 8; ++k)  Gr[k] = ((const f4*)GT_g)[k*64 + lane];

        for (int t = T_EXACT; t < Tdim; ++t) {
            xbw[lane] = x;
            if (lane < 32) rbw[lane] = o0;
            asm volatile("s_waitcnt lgkmcnt(0)" ::: "memory");
            f4 za = {0.f,0.f,0.f,0.f}, xa = {0.f,0.f,0.f,0.f};
            #pragma unroll
            for (int k = 0; k < 16; ++k) {
                f4 xv = xb4[k];
                za += Hr4[k] * xv;
                xa += Ar[k] * xv;
            }
            #pragma unroll
            for (int k = 0; k < 8; ++k) xa += Gr[k] * rb4[k];
            float z = (za[0]+za[1]) + (za[2]+za[3]);
            if (lane < 32) out_b[t*Mdim + lane] = z;
            o0 = o1;
            if (t + 2 < Tdim) o1 = obs_b[(t+2)*Mdim + m];
            x = (xa[0]+xa[1]) + (xa[2]+xa[3]);
        }
    }
}

// ---------------------------------------------------------------------------
extern "C" void kernel_launch(void* const* d_in, const int* in_sizes, int n_in,
                              void* d_out, int out_size, void* d_ws, size_t ws_size,
                              hipStream_t stream)
{
    const float* obs = (const float*)d_in[0];
    const float* F   = (const float*)d_in[1];
    const float* H   = (const float*)d_in[2];
    const float* Q   = (const float*)d_in[3];
    const float* R   = (const float*)d_in[4];
    const float* x0  = (const float*)d_in[5];
    const float* P0  = (const float*)d_in[6];
    float* out = (float*)d_out;

    // ws: K_T (192*64*32 f32 = 1.5 MiB) | AT (16 KB) @ +2 MiB | GT (8 KB)
    float* K_T  = (float*)d_ws;
    float* AT_g = (float*)((char*)d_ws + (2u << 20));
    float* GT_g = (float*)((char*)d_ws + (2u << 20) + 64*64*sizeof(float));

    hipLaunchKernelGGL(riccati_kernel, dim3(1), dim3(1024), 0, stream,
                       F, H, Q, R, P0, K_T, AT_g, GT_g);
    hipLaunchKernelGGL(filter_kernel, dim3(32), dim3(512), 0, stream,
                       obs, F, H, x0, K_T, AT_g, GT_g, out);
}

// Round 6
// 2402.875 us; speedup vs baseline: 1.5229x; 1.5229x over previous
//
#include <hip/hip_runtime.h>

// Kalman filter, B=256 T=512 S=64 M=32.
// Kernel 1 (1 WG, 256 thr): batch-independent Riccati recursion, 4-row f4
// register-blocked matmuls (LDS-BW bound -> B-operand read once per 4 rows;
// all A-operands f4 from bank-padded copies). Converged Newton-Schulz inverse
// (round-5 logic: TOL 4e-4, caps {40,24,8}, rescue). Runs T_EXACT=128 steps
// (transient ~0.9^256 ~ 2e-6 beyond), then emits closed-loop A=F(I-KH), G=FK.
// Kernel 2 (256 blocks x 64 thr, one wave per batch on its own CU): linear
// state recursion; exact K_t phase then frozen A/G phase (round-4-proven).

#define Sdim 64
#define Mdim 32
#define Tdim 512
#define T_EXACT 128

#define NEWTON_TOL 4e-4f

typedef float f4 __attribute__((ext_vector_type(4)));

// ---------------------------------------------------------------------------
// Kernel 1: Riccati recursion (single workgroup, 256 threads)
// ---------------------------------------------------------------------------
__global__ __launch_bounds__(256)
void riccati_kernel(const float* __restrict__ F, const float* __restrict__ H,
                    const float* __restrict__ Q, const float* __restrict__ R,
                    const float* __restrict__ P0,
                    float* __restrict__ K_T,      // [T_EXACT][64][32] f32
                    float* __restrict__ AT_g,     // [16][64] f4 (A[l][4j+c] at [j][l])
                    float* __restrict__ GT_g)     // [8][64]  f4
{
    // padded layouts: rows of stride 17 f4 (68 floats) or 9 f4 (36 floats)
    // make every A-operand a conflict-free b128 row read.
    __shared__ __align__(16) float Ff [64*68];   // F, stride 17 f4
    __shared__ __align__(16) float FTs[64*64];   // F^T, flat [k][16 f4]
    __shared__ __align__(16) float Hp [32*68];   // H, stride 17 f4
    __shared__ __align__(16) float Ps [64*64];   // P, flat [r][16 f4]
    __shared__ __align__(16) float Qs [64*64];   // Q, flat
    __shared__ __align__(16) float Gs [64*68];   // F*P scratch, stride 17 f4 (FK @33 in emission)
    __shared__ __align__(16) float HPp[32*68];   // H*P, stride 17 f4
    __shared__ __align__(16) float Smp[32*36];   // Sm, stride 9 f4
    __shared__ __align__(16) float Ya [32*36];   // Y ping
    __shared__ __align__(16) float Yb [32*36];   // Y pong
    __shared__ __align__(16) float T1p[32*36];   // Sm*Y
    __shared__ __align__(16) float KT36[64*36];  // K'^T: KT36[s*36+m] = K'[m][s]
    __shared__ int red_a, restarted;

    const int tid = threadIdx.x;
    f4* Ff4   = (f4*)Ff;
    f4* FT4   = (f4*)FTs;
    f4* Hp4   = (f4*)Hp;
    f4* Ps4   = (f4*)Ps;
    f4* Qs4   = (f4*)Qs;
    f4* Gs4   = (f4*)Gs;
    f4* HPp4  = (f4*)HPp;
    f4* Smp4  = (f4*)Smp;
    f4* T1p4  = (f4*)T1p;
    f4* KT364 = (f4*)KT36;
    f4* KT_g4 = (f4*)K_T;
    f4* AT_g4 = (f4*)AT_g;
    f4* GT_g4 = (f4*)GT_g;

    // ---- load
    for (int i = tid; i < 64*64; i += 256) {
        int r = i >> 6, c = i & 63;
        float v = F[i];
        Ff[r*68 + c]  = v;
        FTs[c*64 + r] = v;          // FT[k][l] = F[l][k]
        Ps[i] = P0[i];
        Qs[i] = Q[i];
    }
    for (int i = tid; i < 32*64; i += 256) {
        int m = i >> 6, c = i & 63;
        Hp[m*68 + c] = H[i];
    }
    __syncthreads();

    const int rg  = tid >> 4;      // 0..15 (64-row phases: rows rg+16q)
    const int j4f = tid & 15;      // f4 col 0..15
    const int iN  = tid >> 3;      // 0..31 (NS row)
    const int j4N = tid & 7;       // NS f4 col 0..7

    // phase f: Gs = F * Ps
    auto PH_F = [&]() {
        f4 a0={0,0,0,0}, a1={0,0,0,0}, a2={0,0,0,0}, a3={0,0,0,0};
        #pragma unroll 4
        for (int k4 = 0; k4 < 16; ++k4) {
            f4 b0 = Ps4[(k4*4+0)*16 + j4f];
            f4 b1 = Ps4[(k4*4+1)*16 + j4f];
            f4 b2 = Ps4[(k4*4+2)*16 + j4f];
            f4 b3 = Ps4[(k4*4+3)*16 + j4f];
            f4 fa;
            fa = Ff4[(rg    )*17 + k4]; a0 += fa.x*b0 + fa.y*b1 + fa.z*b2 + fa.w*b3;
            fa = Ff4[(rg+16)*17 + k4]; a1 += fa.x*b0 + fa.y*b1 + fa.z*b2 + fa.w*b3;
            fa = Ff4[(rg+32)*17 + k4]; a2 += fa.x*b0 + fa.y*b1 + fa.z*b2 + fa.w*b3;
            fa = Ff4[(rg+48)*17 + k4]; a3 += fa.x*b0 + fa.y*b1 + fa.z*b2 + fa.w*b3;
        }
        Gs4[(rg    )*17 + j4f] = a0;
        Gs4[(rg+16)*17 + j4f] = a1;
        Gs4[(rg+32)*17 + j4f] = a2;
        Gs4[(rg+48)*17 + j4f] = a3;
    };
    // phase g: Ps = Gs * F^T + Q
    auto PH_G = [&]() {
        f4 a0 = Qs4[(rg    )*16 + j4f];
        f4 a1 = Qs4[(rg+16)*16 + j4f];
        f4 a2 = Qs4[(rg+32)*16 + j4f];
        f4 a3 = Qs4[(rg+48)*16 + j4f];
        #pragma unroll 4
        for (int k4 = 0; k4 < 16; ++k4) {
            f4 b0 = FT4[(k4*4+0)*16 + j4f];
            f4 b1 = FT4[(k4*4+1)*16 + j4f];
            f4 b2 = FT4[(k4*4+2)*16 + j4f];
            f4 b3 = FT4[(k4*4+3)*16 + j4f];
            f4 ga;
            ga = Gs4[(rg    )*17 + k4]; a0 += ga.x*b0 + ga.y*b1 + ga.z*b2 + ga.w*b3;
            ga = Gs4[(rg+16)*17 + k4]; a1 += ga.x*b0 + ga.y*b1 + ga.z*b2 + ga.w*b3;
            ga = Gs4[(rg+32)*17 + k4]; a2 += ga.x*b0 + ga.y*b1 + ga.z*b2 + ga.w*b3;
            ga = Gs4[(rg+48)*17 + k4]; a3 += ga.x*b0 + ga.y*b1 + ga.z*b2 + ga.w*b3;
        }
        Ps4[(rg    )*16 + j4f] = a0;
        Ps4[(rg+16)*16 + j4f] = a1;
        Ps4[(rg+32)*16 + j4f] = a2;
        Ps4[(rg+48)*16 + j4f] = a3;
    };

    // initial predict: P = F P0 F^T + Q
    PH_F(); __syncthreads();
    PH_G(); __syncthreads();

    f4* Ycur4 = (f4*)Ya;
    f4* Yalt4 = (f4*)Yb;
    float* YcurS = Ya;

    for (int t = 0; t < T_EXACT; ++t) {
        // --- a: HP = H * P (rows m = mg+8q), 128 threads
        if (tid < 128) {
            int mg = tid >> 4, j4 = tid & 15;
            f4 a0={0,0,0,0}, a1={0,0,0,0}, a2={0,0,0,0}, a3={0,0,0,0};
            #pragma unroll 4
            for (int k4 = 0; k4 < 16; ++k4) {
                f4 b0 = Ps4[(k4*4+0)*16 + j4];
                f4 b1 = Ps4[(k4*4+1)*16 + j4];
                f4 b2 = Ps4[(k4*4+2)*16 + j4];
                f4 b3 = Ps4[(k4*4+3)*16 + j4];
                f4 ha;
                ha = Hp4[(mg    )*17 + k4]; a0 += ha.x*b0 + ha.y*b1 + ha.z*b2 + ha.w*b3;
                ha = Hp4[(mg+ 8)*17 + k4]; a1 += ha.x*b0 + ha.y*b1 + ha.z*b2 + ha.w*b3;
                ha = Hp4[(mg+16)*17 + k4]; a2 += ha.x*b0 + ha.y*b1 + ha.z*b2 + ha.w*b3;
                ha = Hp4[(mg+24)*17 + k4]; a3 += ha.x*b0 + ha.y*b1 + ha.z*b2 + ha.w*b3;
            }
            HPp4[(mg    )*17 + j4] = a0;
            HPp4[(mg+ 8)*17 + j4] = a1;
            HPp4[(mg+16)*17 + j4] = a2;
            HPp4[(mg+24)*17 + j4] = a3;
        }
        __syncthreads();

        // --- b: Sm = HP H^T + R (f4 dot along s)
        {
            int i = tid >> 3, jg = tid & 7;
            float s0=0, s1=0, s2=0, s3=0;
            #pragma unroll 4
            for (int s4 = 0; s4 < 16; ++s4) {
                f4 hp = HPp4[i*17 + s4];
                f4 h0 = Hp4[(jg    )*17 + s4];
                f4 h1 = Hp4[(jg+ 8)*17 + s4];
                f4 h2 = Hp4[(jg+16)*17 + s4];
                f4 h3 = Hp4[(jg+24)*17 + s4];
                s0 += hp.x*h0.x + hp.y*h0.y + hp.z*h0.z + hp.w*h0.w;
                s1 += hp.x*h1.x + hp.y*h1.y + hp.z*h1.z + hp.w*h1.w;
                s2 += hp.x*h2.x + hp.y*h2.y + hp.z*h2.z + hp.w*h2.w;
                s3 += hp.x*h3.x + hp.y*h3.y + hp.z*h3.z + hp.w*h3.w;
            }
            Smp[i*36 + jg     ] = s0 + R[i*32 + jg     ];
            Smp[i*36 + jg +  8] = s1 + R[i*32 + jg +  8];
            Smp[i*36 + jg + 16] = s2 + R[i*32 + jg + 16];
            Smp[i*36 + jg + 24] = s3 + R[i*32 + jg + 24];
            if (tid == 0) { red_a = 0; restarted = 0; }
        }
        __syncthreads();

        // --- Newton init (t==0): Y = I / max_row_sum(Sm)
        if (t == 0) {
            float rs = 0.f;
            #pragma unroll
            for (int c = 0; c < 4; ++c) rs += fabsf(Smp[iN*36 + j4N*4 + c]);
            rs += __shfl_xor(rs, 1, 64);
            rs += __shfl_xor(rs, 2, 64);
            rs += __shfl_xor(rs, 4, 64);
            if ((tid & 7) == 0) atomicMax(&red_a, __float_as_int(rs));
            __syncthreads();
            float inv = 1.0f / __int_as_float(red_a);
            f4 y;
            y.x = (j4N*4+0 == iN) ? inv : 0.f;
            y.y = (j4N*4+1 == iN) ? inv : 0.f;
            y.z = (j4N*4+2 == iN) ? inv : 0.f;
            y.w = (j4N*4+3 == iN) ? inv : 0.f;
            Ycur4[iN*9 + j4N] = y;
            if (tid == 0) red_a = 0;
            __syncthreads();
        }

        // --- Newton-Schulz (check-first + rescue; round-5 semantics)
        const int cap = (t == 0) ? 40 : (t <= 8 ? 24 : 8);
        for (int it = 0; it < cap; ++it) {
            f4 acc = {0,0,0,0};
            #pragma unroll
            for (int k4 = 0; k4 < 8; ++k4) {
                f4 a  = Smp4[iN*9 + k4];
                f4 b0 = Ycur4[(k4*4+0)*9 + j4N];
                f4 b1 = Ycur4[(k4*4+1)*9 + j4N];
                f4 b2 = Ycur4[(k4*4+2)*9 + j4N];
                f4 b3 = Ycur4[(k4*4+3)*9 + j4N];
                acc += a.x*b0 + a.y*b1 + a.z*b2 + a.w*b3;
            }
            T1p4[iN*9 + j4N] = acc;
            float e0 =            fabsf(((j4N*4+0==iN)?1.f:0.f) - acc.x);
            e0 = fmaxf(e0, fabsf(((j4N*4+1==iN)?1.f:0.f) - acc.y));
            e0 = fmaxf(e0, fabsf(((j4N*4+2==iN)?1.f:0.f) - acc.z));
            e0 = fmaxf(e0, fabsf(((j4N*4+3==iN)?1.f:0.f) - acc.w));
            #pragma unroll
            for (int off = 32; off; off >>= 1) e0 = fmaxf(e0, __shfl_xor(e0, off, 64));
            if ((tid & 63) == 0) atomicMax(&red_a, __float_as_int(e0));
            __syncthreads();
            float resid = __int_as_float(red_a);           // uniform
            if (resid < NEWTON_TOL) break;
            bool bad = !(resid < 1e30f);
            if ((bad || resid > 0.9f) && restarted == 0) { // rescue re-init
                if (tid == 0) red_a = 0;
                __syncthreads();
                float rs = 0.f;
                #pragma unroll
                for (int c = 0; c < 4; ++c) rs += fabsf(Smp[iN*36 + j4N*4 + c]);
                rs += __shfl_xor(rs, 1, 64);
                rs += __shfl_xor(rs, 2, 64);
                rs += __shfl_xor(rs, 4, 64);
                if ((tid & 7) == 0) atomicMax(&red_a, __float_as_int(rs));
                __syncthreads();
                float inv = 1.0f / __int_as_float(red_a);
                f4 y;
                y.x = (j4N*4+0 == iN) ? inv : 0.f;
                y.y = (j4N*4+1 == iN) ? inv : 0.f;
                y.z = (j4N*4+2 == iN) ? inv : 0.f;
                y.w = (j4N*4+3 == iN) ? inv : 0.f;
                Ycur4[iN*9 + j4N] = y;
                if (tid == 0) { restarted = 1; red_a = 0; }
                __syncthreads();
                continue;
            }
            f4 up = 2.f * Ycur4[iN*9 + j4N];
            #pragma unroll
            for (int k4 = 0; k4 < 8; ++k4) {
                f4 a  = Ycur4[iN*9 + k4];
                f4 b0 = T1p4[(k4*4+0)*9 + j4N];
                f4 b1 = T1p4[(k4*4+1)*9 + j4N];
                f4 b2 = T1p4[(k4*4+2)*9 + j4N];
                f4 b3 = T1p4[(k4*4+3)*9 + j4N];
                up -= a.x*b0 + a.y*b1 + a.z*b2 + a.w*b3;
            }
            Yalt4[iN*9 + j4N] = up;
            if (tid == 0) red_a = 0;
            __syncthreads();
            f4* tmp = Ycur4; Ycur4 = Yalt4; Yalt4 = tmp;
        }

        // --- d: K' = Y * HP  ->  KT36[s][m] = K'[m][s]   (128 threads)
        if (tid < 128) {
            int mg = tid >> 4, j4 = tid & 15;
            f4 a0={0,0,0,0}, a1={0,0,0,0}, a2={0,0,0,0}, a3={0,0,0,0};
            #pragma unroll
            for (int n4 = 0; n4 < 8; ++n4) {
                f4 b0 = HPp4[(n4*4+0)*17 + j4];
                f4 b1 = HPp4[(n4*4+1)*17 + j4];
                f4 b2 = HPp4[(n4*4+2)*17 + j4];
                f4 b3 = HPp4[(n4*4+3)*17 + j4];
                f4 ya;
                ya = Ycur4[(mg    )*9 + n4]; a0 += ya.x*b0 + ya.y*b1 + ya.z*b2 + ya.w*b3;
                ya = Ycur4[(mg+ 8)*9 + n4]; a1 += ya.x*b0 + ya.y*b1 + ya.z*b2 + ya.w*b3;
                ya = Ycur4[(mg+16)*9 + n4]; a2 += ya.x*b0 + ya.y*b1 + ya.z*b2 + ya.w*b3;
                ya = Ycur4[(mg+24)*9 + n4]; a3 += ya.x*b0 + ya.y*b1 + ya.z*b2 + ya.w*b3;
            }
            #pragma unroll
            for (int c = 0; c < 4; ++c) {
                KT36[(j4*4+c)*36 + mg     ] = a0[c];
                KT36[(j4*4+c)*36 + mg +  8] = a1[c];
                KT36[(j4*4+c)*36 + mg + 16] = a2[c];
                KT36[(j4*4+c)*36 + mg + 24] = a3[c];
            }
        }
        __syncthreads();

        // --- store K^T[t] to global, [s][m4] f4 coalesced
        for (int idx = tid; idx < 512; idx += 256) {
            int s = idx >> 3, m4 = idx & 7;
            f4 v = { KT36[s*36 + m4*4 + 0], KT36[s*36 + m4*4 + 1],
                     KT36[s*36 + m4*4 + 2], KT36[s*36 + m4*4 + 3] };
            KT_g4[(size_t)t*512 + idx] = v;
        }

        if (t == T_EXACT - 1) {
            // --- emit closed-loop A = F - FK*H, G = FK (FK = F*K'^T)
            for (int idx = tid; idx < 64*32; idx += 256) {
                int l = idx >> 5, m = idx & 31;
                float acc = 0.f;
                #pragma unroll 8
                for (int s = 0; s < 64; ++s) acc += Ff[l*68 + s] * KT36[s*36 + m];
                Gs[l*33 + m] = acc;
            }
            __syncthreads();
            for (int idx = tid; idx < 1024; idx += 256) {
                int j4 = idx >> 6, l = idx & 63;
                f4 aa;
                #pragma unroll
                for (int c = 0; c < 4; ++c) {
                    int j = j4*4 + c;
                    float a = Ff[l*68 + j];
                    #pragma unroll 8
                    for (int m = 0; m < 32; ++m) a -= Gs[l*33 + m] * Hp[m*68 + j];
                    aa[c] = a;
                }
                AT_g4[j4*64 + l] = aa;
            }
            for (int idx = tid; idx < 512; idx += 256) {
                int m4 = idx >> 6, l = idx & 63;
                f4 gg = { Gs[l*33 + m4*4 + 0], Gs[l*33 + m4*4 + 1],
                          Gs[l*33 + m4*4 + 2], Gs[l*33 + m4*4 + 3] };
                GT_g4[m4*64 + l] = gg;
            }
            break;
        }

        // --- e: P -= K'^T * HP (own-element in place)
        {
            f4 a0 = Ps4[(rg    )*16 + j4f];
            f4 a1 = Ps4[(rg+16)*16 + j4f];
            f4 a2 = Ps4[(rg+32)*16 + j4f];
            f4 a3 = Ps4[(rg+48)*16 + j4f];
            #pragma unroll
            for (int m4 = 0; m4 < 8; ++m4) {
                f4 b0 = HPp4[(m4*4+0)*17 + j4f];
                f4 b1 = HPp4[(m4*4+1)*17 + j4f];
                f4 b2 = HPp4[(m4*4+2)*17 + j4f];
                f4 b3 = HPp4[(m4*4+3)*17 + j4f];
                f4 ka;
                ka = KT364[(rg    )*9 + m4]; a0 -= ka.x*b0 + ka.y*b1 + ka.z*b2 + ka.w*b3;
                ka = KT364[(rg+16)*9 + m4]; a1 -= ka.x*b0 + ka.y*b1 + ka.z*b2 + ka.w*b3;
                ka = KT364[(rg+32)*9 + m4]; a2 -= ka.x*b0 + ka.y*b1 + ka.z*b2 + ka.w*b3;
                ka = KT364[(rg+48)*9 + m4]; a3 -= ka.x*b0 + ka.y*b1 + ka.z*b2 + ka.w*b3;
            }
            Ps4[(rg    )*16 + j4f] = a0;
            Ps4[(rg+16)*16 + j4f] = a1;
            Ps4[(rg+32)*16 + j4f] = a2;
            Ps4[(rg+48)*16 + j4f] = a3;
        }
        __syncthreads();

        PH_F(); __syncthreads();
        PH_G(); __syncthreads();
    }
    (void)YcurS;
}

// ---------------------------------------------------------------------------
// Kernel 2: per-batch state recursion, one wave per batch (256 blocks x 64)
// ---------------------------------------------------------------------------
__global__ __launch_bounds__(64)
void filter_kernel(const float* __restrict__ obs, const float* __restrict__ F,
                   const float* __restrict__ H, const float* __restrict__ x0,
                   const float* __restrict__ K_T, const float* __restrict__ AT_g,
                   const float* __restrict__ GT_g, float* __restrict__ out)
{
    const int lane = threadIdx.x;
    const int b    = blockIdx.x;
    const int m    = lane & 31;

    __shared__ __align__(16) float xb[64];
    __shared__ __align__(16) float rb[32];
    __shared__ __align__(16) float ub[64];
    const f4* xb4 = (const f4*)xb;
    const f4* rb4 = (const f4*)rb;
    const f4* ub4 = (const f4*)ub;

    f4 Fr4[16], Hr4[16];
    #pragma unroll
    for (int k = 0; k < 16; ++k) Fr4[k] = ((const f4*)(F + lane*64))[k];
    #pragma unroll
    for (int k = 0; k < 16; ++k) Hr4[k] = ((const f4*)(H + m*64))[k];

    float x;
    {   // x = F x0 (initial predict)
        f4 a = {0.f,0.f,0.f,0.f};
        #pragma unroll
        for (int k = 0; k < 16; ++k) a += Fr4[k] * ((const f4*)x0)[k];
        x = (a[0]+a[1]) + (a[2]+a[3]);
    }

    const float* obs_b = obs + (size_t)b * (Tdim*Mdim);
    float*       out_b = out + (size_t)b * (Tdim*Mdim);
    float o0 = obs_b[m];
    float o1 = obs_b[Mdim + m];

    const f4* KT4 = (const f4*)K_T;

    // ---- exact phase: t in [0, T_EXACT)
    for (int t = 0; t < T_EXACT; ++t) {
        f4 ku[8];                               // lane's K^T row (128B coalesced)
        #pragma unroll
        for (int k = 0; k < 8; ++k) ku[k] = KT4[(size_t)t*512 + lane*8 + k];

        xb[lane] = x;
        asm volatile("s_waitcnt lgkmcnt(0)" ::: "memory");
        f4 za = {0.f,0.f,0.f,0.f};
        #pragma unroll
        for (int k = 0; k < 16; ++k) za += Hr4[k] * xb4[k];
        float z = (za[0]+za[1]) + (za[2]+za[3]);
        if (lane < 32) { out_b[t*Mdim + lane] = z; rb[lane] = o0 - z; }
        o0 = o1;
        if (t + 2 < Tdim) o1 = obs_b[(t+2)*Mdim + m];
        asm volatile("s_waitcnt lgkmcnt(0)" ::: "memory");
        f4 ua = {0.f,0.f,0.f,0.f};
        #pragma unroll
        for (int k = 0; k < 8; ++k) ua += ku[k] * rb4[k];
        float u = x + (ua[0]+ua[1]) + (ua[2]+ua[3]);
        ub[lane] = u;
        asm volatile("s_waitcnt lgkmcnt(0)" ::: "memory");
        f4 xa = {0.f,0.f,0.f,0.f};
        #pragma unroll
        for (int k = 0; k < 16; ++k) xa += Fr4[k] * ub4[k];
        x = (xa[0]+xa[1]) + (xa[2]+xa[3]);
    }

    // ---- frozen phase: x <- A x + G o, A/G rows in VGPRs
    {
        f4 Ar[16], Gr[8];
        #pragma unroll
        for (int k = 0; k < 16; ++k) Ar[k] = ((const f4*)AT_g)[k*64 + lane];
        #pragma unroll
        for (int k = 0; k < 8; ++k)  Gr[k] = ((const f4*)GT_g)[k*64 + lane];

        for (int t = T_EXACT; t < Tdim; ++t) {
            xb[lane] = x;
            if (lane < 32) rb[lane] = o0;
            asm volatile("s_waitcnt lgkmcnt(0)" ::: "memory");
            f4 za = {0.f,0.f,0.f,0.f}, xa = {0.f,0.f,0.f,0.f};
            #pragma unroll
            for (int k = 0; k < 16; ++k) {
                f4 xv = xb4[k];
                za += Hr4[k] * xv;
                xa += Ar[k] * xv;
            }
            #pragma unroll
            for (int k = 0; k < 8; ++k) xa += Gr[k] * rb4[k];
            float z = (za[0]+za[1]) + (za[2]+za[3]);
            if (lane < 32) out_b[t*Mdim + lane] = z;
            o0 = o1;
            if (t + 2 < Tdim) o1 = obs_b[(t+2)*Mdim + m];
            x = (xa[0]+xa[1]) + (xa[2]+xa[3]);
        }
    }
}

// ---------------------------------------------------------------------------
extern "C" void kernel_launch(void* const* d_in, const int* in_sizes, int n_in,
                              void* d_out, int out_size, void* d_ws, size_t ws_size,
                              hipStream_t stream)
{
    const float* obs = (const float*)d_in[0];
    const float* F   = (const float*)d_in[1];
    const float* H   = (const float*)d_in[2];
    const float* Q   = (const float*)d_in[3];
    const float* R   = (const float*)d_in[4];
    const float* x0  = (const float*)d_in[5];
    const float* P0  = (const float*)d_in[6];
    float* out = (float*)d_out;

    // ws: K_T (128*64*32 f32 = 1 MiB) | AT (16 KB) @ +2 MiB | GT (8 KB)
    float* K_T  = (float*)d_ws;
    float* AT_g = (float*)((char*)d_ws + (2u << 20));
    float* GT_g = (float*)((char*)d_ws + (2u << 20) + 64*64*sizeof(float));

    hipLaunchKernelGGL(riccati_kernel, dim3(1), dim3(256), 0, stream,
                       F, H, Q, R, P0, K_T, AT_g, GT_g);
    hipLaunchKernelGGL(filter_kernel, dim3(256), dim3(64), 0, stream,
                       obs, F, H, x0, K_T, AT_g, GT_g, out);
}

// Round 9
// 1400.961 us; speedup vs baseline: 2.6120x; 1.7152x over previous
//
#include <hip/hip_runtime.h>

// Kalman filter, B=256 T=512 S=64 M=32.
// Kernel 1 (1 WG, 512 thr): batch-independent Riccati recursion. 2-row f4
// register-blocked matmuls (8 waves = 2/SIMD latency hiding + halved B-operand
// re-reads). Converged Newton-Schulz inverse (round-6-proven code, guarded to
// tid<256, barriers unconditional). Runs T_EXACT=96 steps (transient beyond:
// rho^192 ~ 5e-5), then emits closed-loop A=F(I-KH), G=FK.
// Kernel 2 (256 blocks x 64 thr, one wave per batch on its own CU): linear
// state recursion; exact K_t phase then frozen A/G phase (round-4-proven).

#define Sdim 64
#define Mdim 32
#define Tdim 512
#define T_EXACT 96

#define NEWTON_TOL 4e-4f

typedef float f4 __attribute__((ext_vector_type(4)));

// ---------------------------------------------------------------------------
// Kernel 1: Riccati recursion (single workgroup, 512 threads)
// ---------------------------------------------------------------------------
__global__ __launch_bounds__(512)
void riccati_kernel(const float* __restrict__ F, const float* __restrict__ H,
                    const float* __restrict__ Q, const float* __restrict__ R,
                    const float* __restrict__ P0,
                    float* __restrict__ K_T,      // [T_EXACT][64][32] f32
                    float* __restrict__ AT_g,     // [16][64] f4 (A[l][4j+c] at [j][l])
                    float* __restrict__ GT_g)     // [8][64]  f4
{
    __shared__ __align__(16) float Ff [64*68];   // F, stride 17 f4
    __shared__ __align__(16) float FTs[64*64];   // F^T, flat [k][16 f4]
    __shared__ __align__(16) float Hp [32*68];   // H, stride 17 f4
    __shared__ __align__(16) float Ps [64*64];   // P, flat [r][16 f4]
    __shared__ __align__(16) float Qs [64*64];   // Q, flat
    __shared__ __align__(16) float Gs [64*68];   // F*P scratch (FK @33 in emission)
    __shared__ __align__(16) float HPp[32*68];   // H*P, stride 17 f4
    __shared__ __align__(16) float Smp[32*36];   // Sm, stride 9 f4
    __shared__ __align__(16) float Ya [32*36];   // Y ping
    __shared__ __align__(16) float Yb [32*36];   // Y pong
    __shared__ __align__(16) float T1p[32*36];   // Sm*Y
    __shared__ __align__(16) float KT36[64*36];  // K'^T: KT36[s*36+m] = K'[m][s]
    __shared__ int red_a, restarted;

    const int tid = threadIdx.x;
    f4* Ff4   = (f4*)Ff;
    f4* FT4   = (f4*)FTs;
    f4* Hp4   = (f4*)Hp;
    f4* Ps4   = (f4*)Ps;
    f4* Qs4   = (f4*)Qs;
    f4* Gs4   = (f4*)Gs;
    f4* HPp4  = (f4*)HPp;
    f4* Smp4  = (f4*)Smp;
    f4* T1p4  = (f4*)T1p;
    f4* KT364 = (f4*)KT36;
    f4* KT_g4 = (f4*)K_T;
    f4* AT_g4 = (f4*)AT_g;
    f4* GT_g4 = (f4*)GT_g;

    // ---- load
    for (int i = tid; i < 64*64; i += 512) {
        int r = i >> 6, c = i & 63;
        float v = F[i];
        Ff[r*68 + c]  = v;
        FTs[c*64 + r] = v;          // FT[k][l] = F[l][k]
        Ps[i] = P0[i];
        Qs[i] = Q[i];
    }
    for (int i = tid; i < 32*64; i += 512) {
        int m = i >> 6, c = i & 63;
        Hp[m*68 + c] = H[i];
    }
    __syncthreads();

    const int rg  = tid >> 4;      // 0..31 (64-row phases: rows rg, rg+32)
    const int j4f = tid & 15;      // f4 col 0..15
    const int mg  = tid >> 4;      // 0..15 when tid<256 (32-row phases: mg, mg+16)
    const int iN  = tid >> 3;      // 0..31 when tid<256 (NS row)
    const int j4N = tid & 7;       // NS f4 col 0..7

    // phase f: Gs = F * Ps   (2-row: rg, rg+32)
    auto PH_F = [&]() {
        f4 a0={0,0,0,0}, a1={0,0,0,0};
        #pragma unroll 4
        for (int k4 = 0; k4 < 16; ++k4) {
            f4 b0 = Ps4[(k4*4+0)*16 + j4f];
            f4 b1 = Ps4[(k4*4+1)*16 + j4f];
            f4 b2 = Ps4[(k4*4+2)*16 + j4f];
            f4 b3 = Ps4[(k4*4+3)*16 + j4f];
            f4 fa;
            fa = Ff4[(rg    )*17 + k4]; a0 += fa.x*b0 + fa.y*b1 + fa.z*b2 + fa.w*b3;
            fa = Ff4[(rg+32)*17 + k4]; a1 += fa.x*b0 + fa.y*b1 + fa.z*b2 + fa.w*b3;
        }
        Gs4[(rg    )*17 + j4f] = a0;
        Gs4[(rg+32)*17 + j4f] = a1;
    };
    // phase g: Ps = Gs * F^T + Q
    auto PH_G = [&]() {
        f4 a0 = Qs4[(rg    )*16 + j4f];
        f4 a1 = Qs4[(rg+32)*16 + j4f];
        #pragma unroll 4
        for (int k4 = 0; k4 < 16; ++k4) {
            f4 b0 = FT4[(k4*4+0)*16 + j4f];
            f4 b1 = FT4[(k4*4+1)*16 + j4f];
            f4 b2 = FT4[(k4*4+2)*16 + j4f];
            f4 b3 = FT4[(k4*4+3)*16 + j4f];
            f4 ga;
            ga = Gs4[(rg    )*17 + k4]; a0 += ga.x*b0 + ga.y*b1 + ga.z*b2 + ga.w*b3;
            ga = Gs4[(rg+32)*17 + k4]; a1 += ga.x*b0 + ga.y*b1 + ga.z*b2 + ga.w*b3;
        }
        Ps4[(rg    )*16 + j4f] = a0;
        Ps4[(rg+32)*16 + j4f] = a1;
    };

    // initial predict: P = F P0 F^T + Q
    PH_F(); __syncthreads();
    PH_G(); __syncthreads();

    f4* Ycur4 = (f4*)Ya;
    f4* Yalt4 = (f4*)Yb;

    for (int t = 0; t < T_EXACT; ++t) {
        // --- a: HP = H * P (2-row: mg, mg+16), 256 threads
        if (tid < 256) {
            f4 a0={0,0,0,0}, a1={0,0,0,0};
            #pragma unroll 4
            for (int k4 = 0; k4 < 16; ++k4) {
                f4 b0 = Ps4[(k4*4+0)*16 + j4f];
                f4 b1 = Ps4[(k4*4+1)*16 + j4f];
                f4 b2 = Ps4[(k4*4+2)*16 + j4f];
                f4 b3 = Ps4[(k4*4+3)*16 + j4f];
                f4 ha;
                ha = Hp4[(mg    )*17 + k4]; a0 += ha.x*b0 + ha.y*b1 + ha.z*b2 + ha.w*b3;
                ha = Hp4[(mg+16)*17 + k4]; a1 += ha.x*b0 + ha.y*b1 + ha.z*b2 + ha.w*b3;
            }
            HPp4[(mg    )*17 + j4f] = a0;
            HPp4[(mg+16)*17 + j4f] = a1;
        }
        __syncthreads();

        // --- b: Sm = HP H^T + R (f4 dot along s), 256 threads
        if (tid < 256) {
            int i = tid >> 3, jg = tid & 7;
            float s0=0, s1=0, s2=0, s3=0;
            #pragma unroll 4
            for (int s4 = 0; s4 < 16; ++s4) {
                f4 hp = HPp4[i*17 + s4];
                f4 h0 = Hp4[(jg    )*17 + s4];
                f4 h1 = Hp4[(jg+ 8)*17 + s4];
                f4 h2 = Hp4[(jg+16)*17 + s4];
                f4 h3 = Hp4[(jg+24)*17 + s4];
                s0 += hp.x*h0.x + hp.y*h0.y + hp.z*h0.z + hp.w*h0.w;
                s1 += hp.x*h1.x + hp.y*h1.y + hp.z*h1.z + hp.w*h1.w;
                s2 += hp.x*h2.x + hp.y*h2.y + hp.z*h2.z + hp.w*h2.w;
                s3 += hp.x*h3.x + hp.y*h3.y + hp.z*h3.z + hp.w*h3.w;
            }
            Smp[i*36 + jg     ] = s0 + R[i*32 + jg     ];
            Smp[i*36 + jg +  8] = s1 + R[i*32 + jg +  8];
            Smp[i*36 + jg + 16] = s2 + R[i*32 + jg + 16];
            Smp[i*36 + jg + 24] = s3 + R[i*32 + jg + 24];
        }
        if (tid == 0) { red_a = 0; restarted = 0; }
        __syncthreads();

        // --- Newton init (t==0): Y = I / max_row_sum(Sm)
        if (t == 0) {
            if (tid < 256) {
                float rs = 0.f;
                #pragma unroll
                for (int c = 0; c < 4; ++c) rs += fabsf(Smp[iN*36 + j4N*4 + c]);
                rs += __shfl_xor(rs, 1, 64);
                rs += __shfl_xor(rs, 2, 64);
                rs += __shfl_xor(rs, 4, 64);
                if ((tid & 7) == 0) atomicMax(&red_a, __float_as_int(rs));
            }
            __syncthreads();
            float inv = 1.0f / __int_as_float(red_a);
            if (tid < 256) {
                f4 y;
                y.x = (j4N*4+0 == iN) ? inv : 0.f;
                y.y = (j4N*4+1 == iN) ? inv : 0.f;
                y.z = (j4N*4+2 == iN) ? inv : 0.f;
                y.w = (j4N*4+3 == iN) ? inv : 0.f;
                Ycur4[iN*9 + j4N] = y;
            }
            if (tid == 0) red_a = 0;
            __syncthreads();
        }

        // --- Newton-Schulz (check-first + rescue; round-6 semantics).
        // ALL 512 threads execute loop control + barriers; compute guarded.
        const int cap = (t == 0) ? 40 : (t <= 8 ? 24 : 8);
        for (int it = 0; it < cap; ++it) {
            if (tid < 256) {
                f4 acc = {0,0,0,0};
                #pragma unroll
                for (int k4 = 0; k4 < 8; ++k4) {
                    f4 a  = Smp4[iN*9 + k4];
                    f4 b0 = Ycur4[(k4*4+0)*9 + j4N];
                    f4 b1 = Ycur4[(k4*4+1)*9 + j4N];
                    f4 b2 = Ycur4[(k4*4+2)*9 + j4N];
                    f4 b3 = Ycur4[(k4*4+3)*9 + j4N];
                    acc += a.x*b0 + a.y*b1 + a.z*b2 + a.w*b3;
                }
                T1p4[iN*9 + j4N] = acc;
                float e0 =     fabsf(((j4N*4+0==iN)?1.f:0.f) - acc.x);
                e0 = fmaxf(e0, fabsf(((j4N*4+1==iN)?1.f:0.f) - acc.y));
                e0 = fmaxf(e0, fabsf(((j4N*4+2==iN)?1.f:0.f) - acc.z));
                e0 = fmaxf(e0, fabsf(((j4N*4+3==iN)?1.f:0.f) - acc.w));
                #pragma unroll
                for (int off = 32; off; off >>= 1) e0 = fmaxf(e0, __shfl_xor(e0, off, 64));
                if ((tid & 63) == 0) atomicMax(&red_a, __float_as_int(e0));
            }
            __syncthreads();
            float resid = __int_as_float(red_a);           // uniform
            if (resid < NEWTON_TOL) break;
            bool bad = !(resid < 1e30f);
            if ((bad || resid > 0.9f) && restarted == 0) { // rescue re-init
                if (tid == 0) red_a = 0;
                __syncthreads();
                if (tid < 256) {
                    float rs = 0.f;
                    #pragma unroll
                    for (int c = 0; c < 4; ++c) rs += fabsf(Smp[iN*36 + j4N*4 + c]);
                    rs += __shfl_xor(rs, 1, 64);
                    rs += __shfl_xor(rs, 2, 64);
                    rs += __shfl_xor(rs, 4, 64);
                    if ((tid & 7) == 0) atomicMax(&red_a, __float_as_int(rs));
                }
                __syncthreads();
                float inv = 1.0f / __int_as_float(red_a);
                if (tid < 256) {
                    f4 y;
                    y.x = (j4N*4+0 == iN) ? inv : 0.f;
                    y.y = (j4N*4+1 == iN) ? inv : 0.f;
                    y.z = (j4N*4+2 == iN) ? inv : 0.f;
                    y.w = (j4N*4+3 == iN) ? inv : 0.f;
                    Ycur4[iN*9 + j4N] = y;
                }
                if (tid == 0) { restarted = 1; red_a = 0; }
                __syncthreads();
                continue;
            }
            if (tid < 256) {
                f4 up = 2.f * Ycur4[iN*9 + j4N];
                #pragma unroll
                for (int k4 = 0; k4 < 8; ++k4) {
                    f4 a  = Ycur4[iN*9 + k4];
                    f4 b0 = T1p4[(k4*4+0)*9 + j4N];
                    f4 b1 = T1p4[(k4*4+1)*9 + j4N];
                    f4 b2 = T1p4[(k4*4+2)*9 + j4N];
                    f4 b3 = T1p4[(k4*4+3)*9 + j4N];
                    up -= a.x*b0 + a.y*b1 + a.z*b2 + a.w*b3;
                }
                Yalt4[iN*9 + j4N] = up;
            }
            if (tid == 0) red_a = 0;
            __syncthreads();
            f4* tmp = Ycur4; Ycur4 = Yalt4; Yalt4 = tmp;   // uniform swap
        }

        // --- d: K' = Y * HP  ->  KT36[s][m] = K'[m][s]  (2-row, 256 threads)
        if (tid < 256) {
            f4 a0={0,0,0,0}, a1={0,0,0,0};
            #pragma unroll
            for (int n4 = 0; n4 < 8; ++n4) {
                f4 b0 = HPp4[(n4*4+0)*17 + j4f];
                f4 b1 = HPp4[(n4*4+1)*17 + j4f];
                f4 b2 = HPp4[(n4*4+2)*17 + j4f];
                f4 b3 = HPp4[(n4*4+3)*17 + j4f];
                f4 ya;
                ya = Ycur4[(mg    )*9 + n4]; a0 += ya.x*b0 + ya.y*b1 + ya.z*b2 + ya.w*b3;
                ya = Ycur4[(mg+16)*9 + n4]; a1 += ya.x*b0 + ya.y*b1 + ya.z*b2 + ya.w*b3;
            }
            #pragma unroll
            for (int c = 0; c < 4; ++c) {
                KT36[(j4f*4+c)*36 + mg     ] = a0[c];
                KT36[(j4f*4+c)*36 + mg + 16] = a1[c];
            }
        }
        __syncthreads();

        // --- store K^T[t] to global, [s][m4] f4 coalesced (512 threads = 512 f4)
        {
            int s = tid >> 3, m4 = tid & 7;
            f4 v = { KT36[s*36 + m4*4 + 0], KT36[s*36 + m4*4 + 1],
                     KT36[s*36 + m4*4 + 2], KT36[s*36 + m4*4 + 3] };
            KT_g4[(size_t)t*512 + tid] = v;
        }

        if (t == T_EXACT - 1) {
            // --- emit closed-loop A = F - FK*H, G = FK (FK = F*K'^T)
            for (int idx = tid; idx < 64*32; idx += 512) {
                int l = idx >> 5, m = idx & 31;
                float acc = 0.f;
                #pragma unroll 8
                for (int s = 0; s < 64; ++s) acc += Ff[l*68 + s] * KT36[s*36 + m];
                Gs[l*33 + m] = acc;
            }
            __syncthreads();
            for (int idx = tid; idx < 1024; idx += 512) {
                int j4 = idx >> 6, l = idx & 63;
                f4 aa;
                #pragma unroll
                for (int c = 0; c < 4; ++c) {
                    int j = j4*4 + c;
                    float a = Ff[l*68 + j];
                    #pragma unroll 8
                    for (int m = 0; m < 32; ++m) a -= Gs[l*33 + m] * Hp[m*68 + j];
                    aa[c] = a;
                }
                AT_g4[j4*64 + l] = aa;
            }
            {
                int m4 = tid >> 6, l = tid & 63;   // 512 threads = 8 x 64
                f4 gg = { Gs[l*33 + m4*4 + 0], Gs[l*33 + m4*4 + 1],
                          Gs[l*33 + m4*4 + 2], Gs[l*33 + m4*4 + 3] };
                GT_g4[m4*64 + l] = gg;
            }
            break;
        }

        // --- e: P -= K'^T * HP (own element, 2-row: rg, rg+32)
        {
            f4 a0 = Ps4[(rg    )*16 + j4f];
            f4 a1 = Ps4[(rg+32)*16 + j4f];
            #pragma unroll
            for (int m4 = 0; m4 < 8; ++m4) {
                f4 b0 = HPp4[(m4*4+0)*17 + j4f];
                f4 b1 = HPp4[(m4*4+1)*17 + j4f];
                f4 b2 = HPp4[(m4*4+2)*17 + j4f];
                f4 b3 = HPp4[(m4*4+3)*17 + j4f];
                f4 ka;
                ka = KT364[(rg    )*9 + m4]; a0 -= ka.x*b0 + ka.y*b1 + ka.z*b2 + ka.w*b3;
                ka = KT364[(rg+32)*9 + m4]; a1 -= ka.x*b0 + ka.y*b1 + ka.z*b2 + ka.w*b3;
            }
            Ps4[(rg    )*16 + j4f] = a0;
            Ps4[(rg+32)*16 + j4f] = a1;
        }
        __syncthreads();

        PH_F(); __syncthreads();
        PH_G(); __syncthreads();
    }
}

// ---------------------------------------------------------------------------
// Kernel 2: per-batch state recursion, one wave per batch (256 blocks x 64)
// ---------------------------------------------------------------------------
__global__ __launch_bounds__(64)
void filter_kernel(const float* __restrict__ obs, const float* __restrict__ F,
                   const float* __restrict__ H, const float* __restrict__ x0,
                   const float* __restrict__ K_T, const float* __restrict__ AT_g,
                   const float* __restrict__ GT_g, float* __restrict__ out)
{
    const int lane = threadIdx.x;
    const int b    = blockIdx.x;
    const int m    = lane & 31;

    __shared__ __align__(16) float xb[64];
    __shared__ __align__(16) float rb[32];
    __shared__ __align__(16) float ub[64];
    const f4* xb4 = (const f4*)xb;
    const f4* rb4 = (const f4*)rb;
    const f4* ub4 = (const f4*)ub;

    f4 Fr4[16], Hr4[16];
    #pragma unroll
    for (int k = 0; k < 16; ++k) Fr4[k] = ((const f4*)(F + lane*64))[k];
    #pragma unroll
    for (int k = 0; k < 16; ++k) Hr4[k] = ((const f4*)(H + m*64))[k];

    float x;
    {   // x = F x0 (initial predict)
        f4 a = {0.f,0.f,0.f,0.f};
        #pragma unroll
        for (int k = 0; k < 16; ++k) a += Fr4[k] * ((const f4*)x0)[k];
        x = (a[0]+a[1]) + (a[2]+a[3]);
    }

    const float* obs_b = obs + (size_t)b * (Tdim*Mdim);
    float*       out_b = out + (size_t)b * (Tdim*Mdim);
    float o0 = obs_b[m];
    float o1 = obs_b[Mdim + m];

    const f4* KT4 = (const f4*)K_T;

    // ---- exact phase: t in [0, T_EXACT)
    for (int t = 0; t < T_EXACT; ++t) {
        f4 ku[8];                               // lane's K^T row (128B coalesced)
        #pragma unroll
        for (int k = 0; k < 8; ++k) ku[k] = KT4[(size_t)t*512 + lane*8 + k];

        xb[lane] = x;
        asm volatile("s_waitcnt lgkmcnt(0)" ::: "memory");
        f4 za = {0.f,0.f,0.f,0.f};
        #pragma unroll
        for (int k = 0; k < 16; ++k) za += Hr4[k] * xb4[k];
        float z = (za[0]+za[1]) + (za[2]+za[3]);
        if (lane < 32) { out_b[t*Mdim + lane] = z; rb[lane] = o0 - z; }
        o0 = o1;
        if (t + 2 < Tdim) o1 = obs_b[(t+2)*Mdim + m];
        asm volatile("s_waitcnt lgkmcnt(0)" ::: "memory");
        f4 ua = {0.f,0.f,0.f,0.f};
        #pragma unroll
        for (int k = 0; k < 8; ++k) ua += ku[k] * rb4[k];
        float u = x + (ua[0]+ua[1]) + (ua[2]+ua[3]);
        ub[lane] = u;
        asm volatile("s_waitcnt lgkmcnt(0)" ::: "memory");
        f4 xa = {0.f,0.f,0.f,0.f};
        #pragma unroll
        for (int k = 0; k < 16; ++k) xa += Fr4[k] * ub4[k];
        x = (xa[0]+xa[1]) + (xa[2]+xa[3]);
    }

    // ---- frozen phase: x <- A x + G o, A/G rows in VGPRs
    {
        f4 Ar[16], Gr[8];
        #pragma unroll
        for (int k = 0; k < 16; ++k) Ar[k] = ((const f4*)AT_g)[k*64 + lane];
        #pragma unroll
        for (int k = 0; k < 8; ++k)  Gr[k] = ((const f4*)GT_g)[k*64 + lane];

        for (int t = T_EXACT; t < Tdim; ++t) {
            xb[lane] = x;
            if (lane < 32) rb[lane] = o0;
            asm volatile("s_waitcnt lgkmcnt(0)" ::: "memory");
            f4 za = {0.f,0.f,0.f,0.f}, xa = {0.f,0.f,0.f,0.f};
            #pragma unroll
            for (int k = 0; k < 16; ++k) {
                f4 xv = xb4[k];
                za += Hr4[k] * xv;
                xa += Ar[k] * xv;
            }
            #pragma unroll
            for (int k = 0; k < 8; ++k) xa += Gr[k] * rb4[k];
            float z = (za[0]+za[1]) + (za[2]+za[3]);
            if (lane < 32) out_b[t*Mdim + lane] = z;
            o0 = o1;
            if (t + 2 < Tdim) o1 = obs_b[(t+2)*Mdim + m];
            x = (xa[0]+xa[1]) + (xa[2]+xa[3]);
        }
    }
}

// ---------------------------------------------------------------------------
extern "C" void kernel_launch(void* const* d_in, const int* in_sizes, int n_in,
                              void* d_out, int out_size, void* d_ws, size_t ws_size,
                              hipStream_t stream)
{
    const float* obs = (const float*)d_in[0];
    const float* F   = (const float*)d_in[1];
    const float* H   = (const float*)d_in[2];
    const float* Q   = (const float*)d_in[3];
    const float* R   = (const float*)d_in[4];
    const float* x0  = (const float*)d_in[5];
    const float* P0  = (const float*)d_in[6];
    float* out = (float*)d_out;

    // ws: K_T (96*64*32 f32 = 768 KB) | AT (16 KB) @ +2 MiB | GT (8 KB)
    float* K_T  = (float*)d_ws;
    float* AT_g = (float*)((char*)d_ws + (2u << 20));
    float* GT_g = (float*)((char*)d_ws + (2u << 20) + 64*64*sizeof(float));

    hipLaunchKernelGGL(riccati_kernel, dim3(1), dim3(512), 0, stream,
                       F, H, Q, R, P0, K_T, AT_g, GT_g);
    hipLaunchKernelGGL(filter_kernel, dim3(256), dim3(64), 0, stream,
                       obs, F, H, x0, K_T, AT_g, GT_g, out);
}

// Round 10
// 1123.659 us; speedup vs baseline: 3.2566x; 1.2468x over previous
//
#include <hip/hip_runtime.h>

// Kalman filter, B=256 T=512 S=64 M=32.
// Kernel 1 (1 WG, 512 thr): batch-independent Riccati recursion. 2-row f4
// register-blocked matmuls (8 waves = 2/SIMD latency hiding + halved B-operand
// re-reads). Converged Newton-Schulz inverse (round-6-proven code, guarded to
// tid<256, barriers unconditional). Runs T_EXACT=64 steps (absmax was
// bit-identical at 192/128/96 -> freeze error below NS noise; transient at 64
// is rho^128 ~ 2e-5), then emits closed-loop A=F(I-KH), G=FK.
// Kernel 2 (256 blocks x 64 thr, one wave per batch on its own CU): linear
// state recursion; exact K_t phase then frozen A/G phase (round-4-proven).

#define Sdim 64
#define Mdim 32
#define Tdim 512
#define T_EXACT 64

#define NEWTON_TOL 4e-4f

typedef float f4 __attribute__((ext_vector_type(4)));

// ---------------------------------------------------------------------------
// Kernel 1: Riccati recursion (single workgroup, 512 threads)
// ---------------------------------------------------------------------------
__global__ __launch_bounds__(512)
void riccati_kernel(const float* __restrict__ F, const float* __restrict__ H,
                    const float* __restrict__ Q, const float* __restrict__ R,
                    const float* __restrict__ P0,
                    float* __restrict__ K_T,      // [T_EXACT][64][32] f32
                    float* __restrict__ AT_g,     // [16][64] f4 (A[l][4j+c] at [j][l])
                    float* __restrict__ GT_g)     // [8][64]  f4
{
    __shared__ __align__(16) float Ff [64*68];   // F, stride 17 f4
    __shared__ __align__(16) float FTs[64*64];   // F^T, flat [k][16 f4]
    __shared__ __align__(16) float Hp [32*68];   // H, stride 17 f4
    __shared__ __align__(16) float Ps [64*64];   // P, flat [r][16 f4]
    __shared__ __align__(16) float Qs [64*64];   // Q, flat
    __shared__ __align__(16) float Gs [64*68];   // F*P scratch (FK @33 in emission)
    __shared__ __align__(16) float HPp[32*68];   // H*P, stride 17 f4
    __shared__ __align__(16) float Smp[32*36];   // Sm, stride 9 f4
    __shared__ __align__(16) float Ya [32*36];   // Y ping
    __shared__ __align__(16) float Yb [32*36];   // Y pong
    __shared__ __align__(16) float T1p[32*36];   // Sm*Y
    __shared__ __align__(16) float KT36[64*36];  // K'^T: KT36[s*36+m] = K'[m][s]
    __shared__ int red_a, restarted;

    const int tid = threadIdx.x;
    f4* Ff4   = (f4*)Ff;
    f4* FT4   = (f4*)FTs;
    f4* Hp4   = (f4*)Hp;
    f4* Ps4   = (f4*)Ps;
    f4* Qs4   = (f4*)Qs;
    f4* Gs4   = (f4*)Gs;
    f4* HPp4  = (f4*)HPp;
    f4* Smp4  = (f4*)Smp;
    f4* T1p4  = (f4*)T1p;
    f4* KT364 = (f4*)KT36;
    f4* KT_g4 = (f4*)K_T;
    f4* AT_g4 = (f4*)AT_g;
    f4* GT_g4 = (f4*)GT_g;

    // ---- load
    for (int i = tid; i < 64*64; i += 512) {
        int r = i >> 6, c = i & 63;
        float v = F[i];
        Ff[r*68 + c]  = v;
        FTs[c*64 + r] = v;          // FT[k][l] = F[l][k]
        Ps[i] = P0[i];
        Qs[i] = Q[i];
    }
    for (int i = tid; i < 32*64; i += 512) {
        int m = i >> 6, c = i & 63;
        Hp[m*68 + c] = H[i];
    }
    __syncthreads();

    const int rg  = tid >> 4;      // 0..31 (64-row phases: rows rg, rg+32)
    const int j4f = tid & 15;      // f4 col 0..15
    const int mg  = tid >> 4;      // 0..15 when tid<256 (32-row phases: mg, mg+16)
    const int iN  = tid >> 3;      // 0..31 when tid<256 (NS row)
    const int j4N = tid & 7;       // NS f4 col 0..7

    // phase f: Gs = F * Ps   (2-row: rg, rg+32)
    auto PH_F = [&]() {
        f4 a0={0,0,0,0}, a1={0,0,0,0};
        #pragma unroll 8
        for (int k4 = 0; k4 < 16; ++k4) {
            f4 b0 = Ps4[(k4*4+0)*16 + j4f];
            f4 b1 = Ps4[(k4*4+1)*16 + j4f];
            f4 b2 = Ps4[(k4*4+2)*16 + j4f];
            f4 b3 = Ps4[(k4*4+3)*16 + j4f];
            f4 fa;
            fa = Ff4[(rg    )*17 + k4]; a0 += fa.x*b0 + fa.y*b1 + fa.z*b2 + fa.w*b3;
            fa = Ff4[(rg+32)*17 + k4]; a1 += fa.x*b0 + fa.y*b1 + fa.z*b2 + fa.w*b3;
        }
        Gs4[(rg    )*17 + j4f] = a0;
        Gs4[(rg+32)*17 + j4f] = a1;
    };
    // phase g: Ps = Gs * F^T + Q
    auto PH_G = [&]() {
        f4 a0 = Qs4[(rg    )*16 + j4f];
        f4 a1 = Qs4[(rg+32)*16 + j4f];
        #pragma unroll 8
        for (int k4 = 0; k4 < 16; ++k4) {
            f4 b0 = FT4[(k4*4+0)*16 + j4f];
            f4 b1 = FT4[(k4*4+1)*16 + j4f];
            f4 b2 = FT4[(k4*4+2)*16 + j4f];
            f4 b3 = FT4[(k4*4+3)*16 + j4f];
            f4 ga;
            ga = Gs4[(rg    )*17 + k4]; a0 += ga.x*b0 + ga.y*b1 + ga.z*b2 + ga.w*b3;
            ga = Gs4[(rg+32)*17 + k4]; a1 += ga.x*b0 + ga.y*b1 + ga.z*b2 + ga.w*b3;
        }
        Ps4[(rg    )*16 + j4f] = a0;
        Ps4[(rg+32)*16 + j4f] = a1;
    };

    // initial predict: P = F P0 F^T + Q
    PH_F(); __syncthreads();
    PH_G(); __syncthreads();

    f4* Ycur4 = (f4*)Ya;
    f4* Yalt4 = (f4*)Yb;

    for (int t = 0; t < T_EXACT; ++t) {
        // --- a: HP = H * P (2-row: mg, mg+16), 256 threads
        if (tid < 256) {
            f4 a0={0,0,0,0}, a1={0,0,0,0};
            #pragma unroll 8
            for (int k4 = 0; k4 < 16; ++k4) {
                f4 b0 = Ps4[(k4*4+0)*16 + j4f];
                f4 b1 = Ps4[(k4*4+1)*16 + j4f];
                f4 b2 = Ps4[(k4*4+2)*16 + j4f];
                f4 b3 = Ps4[(k4*4+3)*16 + j4f];
                f4 ha;
                ha = Hp4[(mg    )*17 + k4]; a0 += ha.x*b0 + ha.y*b1 + ha.z*b2 + ha.w*b3;
                ha = Hp4[(mg+16)*17 + k4]; a1 += ha.x*b0 + ha.y*b1 + ha.z*b2 + ha.w*b3;
            }
            HPp4[(mg    )*17 + j4f] = a0;
            HPp4[(mg+16)*17 + j4f] = a1;
        }
        __syncthreads();

        // --- b: Sm = HP H^T + R (f4 dot along s), 256 threads
        if (tid < 256) {
            int i = tid >> 3, jg = tid & 7;
            float s0=0, s1=0, s2=0, s3=0;
            #pragma unroll 8
            for (int s4 = 0; s4 < 16; ++s4) {
                f4 hp = HPp4[i*17 + s4];
                f4 h0 = Hp4[(jg    )*17 + s4];
                f4 h1 = Hp4[(jg+ 8)*17 + s4];
                f4 h2 = Hp4[(jg+16)*17 + s4];
                f4 h3 = Hp4[(jg+24)*17 + s4];
                s0 += hp.x*h0.x + hp.y*h0.y + hp.z*h0.z + hp.w*h0.w;
                s1 += hp.x*h1.x + hp.y*h1.y + hp.z*h1.z + hp.w*h1.w;
                s2 += hp.x*h2.x + hp.y*h2.y + hp.z*h2.z + hp.w*h2.w;
                s3 += hp.x*h3.x + hp.y*h3.y + hp.z*h3.z + hp.w*h3.w;
            }
            Smp[i*36 + jg     ] = s0 + R[i*32 + jg     ];
            Smp[i*36 + jg +  8] = s1 + R[i*32 + jg +  8];
            Smp[i*36 + jg + 16] = s2 + R[i*32 + jg + 16];
            Smp[i*36 + jg + 24] = s3 + R[i*32 + jg + 24];
        }
        if (tid == 0) { red_a = 0; restarted = 0; }
        __syncthreads();

        // --- Newton init (t==0): Y = I / max_row_sum(Sm)
        if (t == 0) {
            if (tid < 256) {
                float rs = 0.f;
                #pragma unroll
                for (int c = 0; c < 4; ++c) rs += fabsf(Smp[iN*36 + j4N*4 + c]);
                rs += __shfl_xor(rs, 1, 64);
                rs += __shfl_xor(rs, 2, 64);
                rs += __shfl_xor(rs, 4, 64);
                if ((tid & 7) == 0) atomicMax(&red_a, __float_as_int(rs));
            }
            __syncthreads();
            float inv = 1.0f / __int_as_float(red_a);
            if (tid < 256) {
                f4 y;
                y.x = (j4N*4+0 == iN) ? inv : 0.f;
                y.y = (j4N*4+1 == iN) ? inv : 0.f;
                y.z = (j4N*4+2 == iN) ? inv : 0.f;
                y.w = (j4N*4+3 == iN) ? inv : 0.f;
                Ycur4[iN*9 + j4N] = y;
            }
            if (tid == 0) red_a = 0;
            __syncthreads();
        }

        // --- Newton-Schulz (check-first + rescue; round-6 semantics).
        // ALL 512 threads execute loop control + barriers; compute guarded.
        const int cap = (t == 0) ? 40 : (t <= 8 ? 24 : 8);
        for (int it = 0; it < cap; ++it) {
            if (tid < 256) {
                f4 acc = {0,0,0,0};
                #pragma unroll
                for (int k4 = 0; k4 < 8; ++k4) {
                    f4 a  = Smp4[iN*9 + k4];
                    f4 b0 = Ycur4[(k4*4+0)*9 + j4N];
                    f4 b1 = Ycur4[(k4*4+1)*9 + j4N];
                    f4 b2 = Ycur4[(k4*4+2)*9 + j4N];
                    f4 b3 = Ycur4[(k4*4+3)*9 + j4N];
                    acc += a.x*b0 + a.y*b1 + a.z*b2 + a.w*b3;
                }
                T1p4[iN*9 + j4N] = acc;
                float e0 =     fabsf(((j4N*4+0==iN)?1.f:0.f) - acc.x);
                e0 = fmaxf(e0, fabsf(((j4N*4+1==iN)?1.f:0.f) - acc.y));
                e0 = fmaxf(e0, fabsf(((j4N*4+2==iN)?1.f:0.f) - acc.z));
                e0 = fmaxf(e0, fabsf(((j4N*4+3==iN)?1.f:0.f) - acc.w));
                #pragma unroll
                for (int off = 32; off; off >>= 1) e0 = fmaxf(e0, __shfl_xor(e0, off, 64));
                if ((tid & 63) == 0) atomicMax(&red_a, __float_as_int(e0));
            }
            __syncthreads();
            float resid = __int_as_float(red_a);           // uniform
            if (resid < NEWTON_TOL) break;
            bool bad = !(resid < 1e30f);
            if ((bad || resid > 0.9f) && restarted == 0) { // rescue re-init
                if (tid == 0) red_a = 0;
                __syncthreads();
                if (tid < 256) {
                    float rs = 0.f;
                    #pragma unroll
                    for (int c = 0; c < 4; ++c) rs += fabsf(Smp[iN*36 + j4N*4 + c]);
                    rs += __shfl_xor(rs, 1, 64);
                    rs += __shfl_xor(rs, 2, 64);
                    rs += __shfl_xor(rs, 4, 64);
                    if ((tid & 7) == 0) atomicMax(&red_a, __float_as_int(rs));
                }
                __syncthreads();
                float inv = 1.0f / __int_as_float(red_a);
                if (tid < 256) {
                    f4 y;
                    y.x = (j4N*4+0 == iN) ? inv : 0.f;
                    y.y = (j4N*4+1 == iN) ? inv : 0.f;
                    y.z = (j4N*4+2 == iN) ? inv : 0.f;
                    y.w = (j4N*4+3 == iN) ? inv : 0.f;
                    Ycur4[iN*9 + j4N] = y;
                }
                if (tid == 0) { restarted = 1; red_a = 0; }
                __syncthreads();
                continue;
            }
            if (tid < 256) {
                f4 up = 2.f * Ycur4[iN*9 + j4N];
                #pragma unroll
                for (int k4 = 0; k4 < 8; ++k4) {
                    f4 a  = Ycur4[iN*9 + k4];
                    f4 b0 = T1p4[(k4*4+0)*9 + j4N];
                    f4 b1 = T1p4[(k4*4+1)*9 + j4N];
                    f4 b2 = T1p4[(k4*4+2)*9 + j4N];
                    f4 b3 = T1p4[(k4*4+3)*9 + j4N];
                    up -= a.x*b0 + a.y*b1 + a.z*b2 + a.w*b3;
                }
                Yalt4[iN*9 + j4N] = up;
            }
            if (tid == 0) red_a = 0;
            __syncthreads();
            f4* tmp = Ycur4; Ycur4 = Yalt4; Yalt4 = tmp;   // uniform swap
        }

        // --- d: K' = Y * HP  ->  KT36[s][m] = K'[m][s]  (2-row, 256 threads)
        if (tid < 256) {
            f4 a0={0,0,0,0}, a1={0,0,0,0};
            #pragma unroll
            for (int n4 = 0; n4 < 8; ++n4) {
                f4 b0 = HPp4[(n4*4+0)*17 + j4f];
                f4 b1 = HPp4[(n4*4+1)*17 + j4f];
                f4 b2 = HPp4[(n4*4+2)*17 + j4f];
                f4 b3 = HPp4[(n4*4+3)*17 + j4f];
                f4 ya;
                ya = Ycur4[(mg    )*9 + n4]; a0 += ya.x*b0 + ya.y*b1 + ya.z*b2 + ya.w*b3;
                ya = Ycur4[(mg+16)*9 + n4]; a1 += ya.x*b0 + ya.y*b1 + ya.z*b2 + ya.w*b3;
            }
            #pragma unroll
            for (int c = 0; c < 4; ++c) {
                KT36[(j4f*4+c)*36 + mg     ] = a0[c];
                KT36[(j4f*4+c)*36 + mg + 16] = a1[c];
            }
        }
        __syncthreads();

        // --- store K^T[t] to global, [s][m4] f4 coalesced (512 threads = 512 f4)
        {
            int s = tid >> 3, m4 = tid & 7;
            f4 v = { KT36[s*36 + m4*4 + 0], KT36[s*36 + m4*4 + 1],
                     KT36[s*36 + m4*4 + 2], KT36[s*36 + m4*4 + 3] };
            KT_g4[(size_t)t*512 + tid] = v;
        }

        if (t == T_EXACT - 1) {
            // --- emit closed-loop A = F - FK*H, G = FK (FK = F*K'^T)
            for (int idx = tid; idx < 64*32; idx += 512) {
                int l = idx >> 5, m = idx & 31;
                float acc = 0.f;
                #pragma unroll 8
                for (int s = 0; s < 64; ++s) acc += Ff[l*68 + s] * KT36[s*36 + m];
                Gs[l*33 + m] = acc;
            }
            __syncthreads();
            for (int idx = tid; idx < 1024; idx += 512) {
                int j4 = idx >> 6, l = idx & 63;
                f4 aa;
                #pragma unroll
                for (int c = 0; c < 4; ++c) {
                    int j = j4*4 + c;
                    float a = Ff[l*68 + j];
                    #pragma unroll 8
                    for (int m = 0; m < 32; ++m) a -= Gs[l*33 + m] * Hp[m*68 + j];
                    aa[c] = a;
                }
                AT_g4[j4*64 + l] = aa;
            }
            {
                int m4 = tid >> 6, l = tid & 63;   // 512 threads = 8 x 64
                f4 gg = { Gs[l*33 + m4*4 + 0], Gs[l*33 + m4*4 + 1],
                          Gs[l*33 + m4*4 + 2], Gs[l*33 + m4*4 + 3] };
                GT_g4[m4*64 + l] = gg;
            }
            break;
        }

        // --- e: P -= K'^T * HP (own element, 2-row: rg, rg+32)
        {
            f4 a0 = Ps4[(rg    )*16 + j4f];
            f4 a1 = Ps4[(rg+32)*16 + j4f];
            #pragma unroll
            for (int m4 = 0; m4 < 8; ++m4) {
                f4 b0 = HPp4[(m4*4+0)*17 + j4f];
                f4 b1 = HPp4[(m4*4+1)*17 + j4f];
                f4 b2 = HPp4[(m4*4+2)*17 + j4f];
                f4 b3 = HPp4[(m4*4+3)*17 + j4f];
                f4 ka;
                ka = KT364[(rg    )*9 + m4]; a0 -= ka.x*b0 + ka.y*b1 + ka.z*b2 + ka.w*b3;
                ka = KT364[(rg+32)*9 + m4]; a1 -= ka.x*b0 + ka.y*b1 + ka.z*b2 + ka.w*b3;
            }
            Ps4[(rg    )*16 + j4f] = a0;
            Ps4[(rg+32)*16 + j4f] = a1;
        }
        __syncthreads();

        PH_F(); __syncthreads();
        PH_G(); __syncthreads();
    }
}

// ---------------------------------------------------------------------------
// Kernel 2: per-batch state recursion, one wave per batch (256 blocks x 64)
// ---------------------------------------------------------------------------
__global__ __launch_bounds__(64)
void filter_kernel(const float* __restrict__ obs, const float* __restrict__ F,
                   const float* __restrict__ H, const float* __restrict__ x0,
                   const float* __restrict__ K_T, const float* __restrict__ AT_g,
                   const float* __restrict__ GT_g, float* __restrict__ out)
{
    const int lane = threadIdx.x;
    const int b    = blockIdx.x;
    const int m    = lane & 31;

    __shared__ __align__(16) float xb[64];
    __shared__ __align__(16) float rb[32];
    __shared__ __align__(16) float ub[64];
    const f4* xb4 = (const f4*)xb;
    const f4* rb4 = (const f4*)rb;
    const f4* ub4 = (const f4*)ub;

    f4 Fr4[16], Hr4[16];
    #pragma unroll
    for (int k = 0; k < 16; ++k) Fr4[k] = ((const f4*)(F + lane*64))[k];
    #pragma unroll
    for (int k = 0; k < 16; ++k) Hr4[k] = ((const f4*)(H + m*64))[k];

    float x;
    {   // x = F x0 (initial predict)
        f4 a = {0.f,0.f,0.f,0.f};
        #pragma unroll
        for (int k = 0; k < 16; ++k) a += Fr4[k] * ((const f4*)x0)[k];
        x = (a[0]+a[1]) + (a[2]+a[3]);
    }

    const float* obs_b = obs + (size_t)b * (Tdim*Mdim);
    float*       out_b = out + (size_t)b * (Tdim*Mdim);
    float o0 = obs_b[m];
    float o1 = obs_b[Mdim + m];

    const f4* KT4 = (const f4*)K_T;

    // ---- exact phase: t in [0, T_EXACT)
    for (int t = 0; t < T_EXACT; ++t) {
        f4 ku[8];                               // lane's K^T row (128B coalesced)
        #pragma unroll
        for (int k = 0; k < 8; ++k) ku[k] = KT4[(size_t)t*512 + lane*8 + k];

        xb[lane] = x;
        asm volatile("s_waitcnt lgkmcnt(0)" ::: "memory");
        f4 za = {0.f,0.f,0.f,0.f};
        #pragma unroll
        for (int k = 0; k < 16; ++k) za += Hr4[k] * xb4[k];
        float z = (za[0]+za[1]) + (za[2]+za[3]);
        if (lane < 32) { out_b[t*Mdim + lane] = z; rb[lane] = o0 - z; }
        o0 = o1;
        if (t + 2 < Tdim) o1 = obs_b[(t+2)*Mdim + m];
        asm volatile("s_waitcnt lgkmcnt(0)" ::: "memory");
        f4 ua = {0.f,0.f,0.f,0.f};
        #pragma unroll
        for (int k = 0; k < 8; ++k) ua += ku[k] * rb4[k];
        float u = x + (ua[0]+ua[1]) + (ua[2]+ua[3]);
        ub[lane] = u;
        asm volatile("s_waitcnt lgkmcnt(0)" ::: "memory");
        f4 xa = {0.f,0.f,0.f,0.f};
        #pragma unroll
        for (int k = 0; k < 16; ++k) xa += Fr4[k] * ub4[k];
        x = (xa[0]+xa[1]) + (xa[2]+xa[3]);
    }

    // ---- frozen phase: x <- A x + G o, A/G rows in VGPRs
    {
        f4 Ar[16], Gr[8];
        #pragma unroll
        for (int k = 0; k < 16; ++k) Ar[k] = ((const f4*)AT_g)[k*64 + lane];
        #pragma unroll
        for (int k = 0; k < 8; ++k)  Gr[k] = ((const f4*)GT_g)[k*64 + lane];

        for (int t = T_EXACT; t < Tdim; ++t) {
            xb[lane] = x;
            if (lane < 32) rb[lane] = o0;
            asm volatile("s_waitcnt lgkmcnt(0)" ::: "memory");
            f4 za = {0.f,0.f,0.f,0.f}, xa = {0.f,0.f,0.f,0.f};
            #pragma unroll
            for (int k = 0; k < 16; ++k) {
                f4 xv = xb4[k];
                za += Hr4[k] * xv;
                xa += Ar[k] * xv;
            }
            #pragma unroll
            for (int k = 0; k < 8; ++k) xa += Gr[k] * rb4[k];
            float z = (za[0]+za[1]) + (za[2]+za[3]);
            if (lane < 32) out_b[t*Mdim + lane] = z;
            o0 = o1;
            if (t + 2 < Tdim) o1 = obs_b[(t+2)*Mdim + m];
            x = (xa[0]+xa[1]) + (xa[2]+xa[3]);
        }
    }
}

// ---------------------------------------------------------------------------
extern "C" void kernel_launch(void* const* d_in, const int* in_sizes, int n_in,
                              void* d_out, int out_size, void* d_ws, size_t ws_size,
                              hipStream_t stream)
{
    const float* obs = (const float*)d_in[0];
    const float* F   = (const float*)d_in[1];
    const float* H   = (const float*)d_in[2];
    const float* Q   = (const float*)d_in[3];
    const float* R   = (const float*)d_in[4];
    const float* x0  = (const float*)d_in[5];
    const float* P0  = (const float*)d_in[6];
    float* out = (float*)d_out;

    // ws: K_T (64*64*32 f32 = 512 KB) | AT (16 KB) @ +2 MiB | GT (8 KB)
    float* K_T  = (float*)d_ws;
    float* AT_g = (float*)((char*)d_ws + (2u << 20));
    float* GT_g = (float*)((char*)d_ws + (2u << 20) + 64*64*sizeof(float));

    hipLaunchKernelGGL(riccati_kernel, dim3(1), dim3(512), 0, stream,
                       F, H, Q, R, P0, K_T, AT_g, GT_g);
    hipLaunchKernelGGL(filter_kernel, dim3(256), dim3(64), 0, stream,
                       obs, F, H, x0, K_T, AT_g, GT_g, out);
}

// Round 11
// 904.033 us; speedup vs baseline: 4.0478x; 1.2429x over previous
//
#include <hip/hip_runtime.h>

// Kalman filter, B=256 T=512 S=64 M=32.
// Kernel 1 (1 WG, 512 thr): batch-independent Riccati recursion. 2-row f4
// register-blocked matmuls, unroll 4 (round-9-proven best: 10.8 us/step;
// unroll 8 regressed to 12.0). Converged Newton-Schulz inverse. Runs
// T_EXACT=48 steps (remaining transient rho^96 ~ 7e-3 -> output err few e-3;
// absmax was bit-identical at 192/128/96/64), then emits A=F(I-KH), G=FK.
// Kernel 2 (256 blocks x 64 thr, one wave per batch on its own CU): linear
// state recursion; exact K_t phase then frozen A/G phase (round-4-proven).

#define Sdim 64
#define Mdim 32
#define Tdim 512
#define T_EXACT 48

#define NEWTON_TOL 4e-4f

typedef float f4 __attribute__((ext_vector_type(4)));

// ---------------------------------------------------------------------------
// Kernel 1: Riccati recursion (single workgroup, 512 threads)
// ---------------------------------------------------------------------------
__global__ __launch_bounds__(512)
void riccati_kernel(const float* __restrict__ F, const float* __restrict__ H,
                    const float* __restrict__ Q, const float* __restrict__ R,
                    const float* __restrict__ P0,
                    float* __restrict__ K_T,      // [T_EXACT][64][32] f32
                    float* __restrict__ AT_g,     // [16][64] f4 (A[l][4j+c] at [j][l])
                    float* __restrict__ GT_g)     // [8][64]  f4
{
    __shared__ __align__(16) float Ff [64*68];   // F, stride 17 f4
    __shared__ __align__(16) float FTs[64*64];   // F^T, flat [k][16 f4]
    __shared__ __align__(16) float Hp [32*68];   // H, stride 17 f4
    __shared__ __align__(16) float Ps [64*64];   // P, flat [r][16 f4]
    __shared__ __align__(16) float Qs [64*64];   // Q, flat
    __shared__ __align__(16) float Gs [64*68];   // F*P scratch (FK @33 in emission)
    __shared__ __align__(16) float HPp[32*68];   // H*P, stride 17 f4
    __shared__ __align__(16) float Smp[32*36];   // Sm, stride 9 f4
    __shared__ __align__(16) float Ya [32*36];   // Y ping
    __shared__ __align__(16) float Yb [32*36];   // Y pong
    __shared__ __align__(16) float T1p[32*36];   // Sm*Y
    __shared__ __align__(16) float KT36[64*36];  // K'^T: KT36[s*36+m] = K'[m][s]
    __shared__ int red_a, restarted;

    const int tid = threadIdx.x;
    f4* Ff4   = (f4*)Ff;
    f4* FT4   = (f4*)FTs;
    f4* Hp4   = (f4*)Hp;
    f4* Ps4   = (f4*)Ps;
    f4* Qs4   = (f4*)Qs;
    f4* Gs4   = (f4*)Gs;
    f4* HPp4  = (f4*)HPp;
    f4* Smp4  = (f4*)Smp;
    f4* T1p4  = (f4*)T1p;
    f4* KT364 = (f4*)KT36;
    f4* KT_g4 = (f4*)K_T;
    f4* AT_g4 = (f4*)AT_g;
    f4* GT_g4 = (f4*)GT_g;

    // ---- load
    for (int i = tid; i < 64*64; i += 512) {
        int r = i >> 6, c = i & 63;
        float v = F[i];
        Ff[r*68 + c]  = v;
        FTs[c*64 + r] = v;          // FT[k][l] = F[l][k]
        Ps[i] = P0[i];
        Qs[i] = Q[i];
    }
    for (int i = tid; i < 32*64; i += 512) {
        int m = i >> 6, c = i & 63;
        Hp[m*68 + c] = H[i];
    }
    __syncthreads();

    const int rg  = tid >> 4;      // 0..31 (64-row phases: rows rg, rg+32)
    const int j4f = tid & 15;      // f4 col 0..15
    const int mg  = tid >> 4;      // 0..15 when tid<256 (32-row phases: mg, mg+16)
    const int iN  = tid >> 3;      // 0..31 when tid<256 (NS row)
    const int j4N = tid & 7;       // NS f4 col 0..7

    // phase f: Gs = F * Ps   (2-row: rg, rg+32)
    auto PH_F = [&]() {
        f4 a0={0,0,0,0}, a1={0,0,0,0};
        #pragma unroll 4
        for (int k4 = 0; k4 < 16; ++k4) {
            f4 b0 = Ps4[(k4*4+0)*16 + j4f];
            f4 b1 = Ps4[(k4*4+1)*16 + j4f];
            f4 b2 = Ps4[(k4*4+2)*16 + j4f];
            f4 b3 = Ps4[(k4*4+3)*16 + j4f];
            f4 fa;
            fa = Ff4[(rg    )*17 + k4]; a0 += fa.x*b0 + fa.y*b1 + fa.z*b2 + fa.w*b3;
            fa = Ff4[(rg+32)*17 + k4]; a1 += fa.x*b0 + fa.y*b1 + fa.z*b2 + fa.w*b3;
        }
        Gs4[(rg    )*17 + j4f] = a0;
        Gs4[(rg+32)*17 + j4f] = a1;
    };
    // phase g: Ps = Gs * F^T + Q
    auto PH_G = [&]() {
        f4 a0 = Qs4[(rg    )*16 + j4f];
        f4 a1 = Qs4[(rg+32)*16 + j4f];
        #pragma unroll 4
        for (int k4 = 0; k4 < 16; ++k4) {
            f4 b0 = FT4[(k4*4+0)*16 + j4f];
            f4 b1 = FT4[(k4*4+1)*16 + j4f];
            f4 b2 = FT4[(k4*4+2)*16 + j4f];
            f4 b3 = FT4[(k4*4+3)*16 + j4f];
            f4 ga;
            ga = Gs4[(rg    )*17 + k4]; a0 += ga.x*b0 + ga.y*b1 + ga.z*b2 + ga.w*b3;
            ga = Gs4[(rg+32)*17 + k4]; a1 += ga.x*b0 + ga.y*b1 + ga.z*b2 + ga.w*b3;
        }
        Ps4[(rg    )*16 + j4f] = a0;
        Ps4[(rg+32)*16 + j4f] = a1;
    };

    // initial predict: P = F P0 F^T + Q
    PH_F(); __syncthreads();
    PH_G(); __syncthreads();

    f4* Ycur4 = (f4*)Ya;
    f4* Yalt4 = (f4*)Yb;

    for (int t = 0; t < T_EXACT; ++t) {
        // --- a: HP = H * P (2-row: mg, mg+16), 256 threads
        if (tid < 256) {
            f4 a0={0,0,0,0}, a1={0,0,0,0};
            #pragma unroll 4
            for (int k4 = 0; k4 < 16; ++k4) {
                f4 b0 = Ps4[(k4*4+0)*16 + j4f];
                f4 b1 = Ps4[(k4*4+1)*16 + j4f];
                f4 b2 = Ps4[(k4*4+2)*16 + j4f];
                f4 b3 = Ps4[(k4*4+3)*16 + j4f];
                f4 ha;
                ha = Hp4[(mg    )*17 + k4]; a0 += ha.x*b0 + ha.y*b1 + ha.z*b2 + ha.w*b3;
                ha = Hp4[(mg+16)*17 + k4]; a1 += ha.x*b0 + ha.y*b1 + ha.z*b2 + ha.w*b3;
            }
            HPp4[(mg    )*17 + j4f] = a0;
            HPp4[(mg+16)*17 + j4f] = a1;
        }
        __syncthreads();

        // --- b: Sm = HP H^T + R (f4 dot along s), 256 threads
        if (tid < 256) {
            int i = tid >> 3, jg = tid & 7;
            float s0=0, s1=0, s2=0, s3=0;
            #pragma unroll 4
            for (int s4 = 0; s4 < 16; ++s4) {
                f4 hp = HPp4[i*17 + s4];
                f4 h0 = Hp4[(jg    )*17 + s4];
                f4 h1 = Hp4[(jg+ 8)*17 + s4];
                f4 h2 = Hp4[(jg+16)*17 + s4];
                f4 h3 = Hp4[(jg+24)*17 + s4];
                s0 += hp.x*h0.x + hp.y*h0.y + hp.z*h0.z + hp.w*h0.w;
                s1 += hp.x*h1.x + hp.y*h1.y + hp.z*h1.z + hp.w*h1.w;
                s2 += hp.x*h2.x + hp.y*h2.y + hp.z*h2.z + hp.w*h2.w;
                s3 += hp.x*h3.x + hp.y*h3.y + hp.z*h3.z + hp.w*h3.w;
            }
            Smp[i*36 + jg     ] = s0 + R[i*32 + jg     ];
            Smp[i*36 + jg +  8] = s1 + R[i*32 + jg +  8];
            Smp[i*36 + jg + 16] = s2 + R[i*32 + jg + 16];
            Smp[i*36 + jg + 24] = s3 + R[i*32 + jg + 24];
        }
        if (tid == 0) { red_a = 0; restarted = 0; }
        __syncthreads();

        // --- Newton init (t==0): Y = I / max_row_sum(Sm)
        if (t == 0) {
            if (tid < 256) {
                float rs = 0.f;
                #pragma unroll
                for (int c = 0; c < 4; ++c) rs += fabsf(Smp[iN*36 + j4N*4 + c]);
                rs += __shfl_xor(rs, 1, 64);
                rs += __shfl_xor(rs, 2, 64);
                rs += __shfl_xor(rs, 4, 64);
                if ((tid & 7) == 0) atomicMax(&red_a, __float_as_int(rs));
            }
            __syncthreads();
            float inv = 1.0f / __int_as_float(red_a);
            if (tid < 256) {
                f4 y;
                y.x = (j4N*4+0 == iN) ? inv : 0.f;
                y.y = (j4N*4+1 == iN) ? inv : 0.f;
                y.z = (j4N*4+2 == iN) ? inv : 0.f;
                y.w = (j4N*4+3 == iN) ? inv : 0.f;
                Ycur4[iN*9 + j4N] = y;
            }
            if (tid == 0) red_a = 0;
            __syncthreads();
        }

        // --- Newton-Schulz (check-first + rescue; round-6 semantics).
        // ALL 512 threads execute loop control + barriers; compute guarded.
        const int cap = (t == 0) ? 40 : (t <= 8 ? 24 : 8);
        for (int it = 0; it < cap; ++it) {
            if (tid < 256) {
                f4 acc = {0,0,0,0};
                #pragma unroll
                for (int k4 = 0; k4 < 8; ++k4) {
                    f4 a  = Smp4[iN*9 + k4];
                    f4 b0 = Ycur4[(k4*4+0)*9 + j4N];
                    f4 b1 = Ycur4[(k4*4+1)*9 + j4N];
                    f4 b2 = Ycur4[(k4*4+2)*9 + j4N];
                    f4 b3 = Ycur4[(k4*4+3)*9 + j4N];
                    acc += a.x*b0 + a.y*b1 + a.z*b2 + a.w*b3;
                }
                T1p4[iN*9 + j4N] = acc;
                float e0 =     fabsf(((j4N*4+0==iN)?1.f:0.f) - acc.x);
                e0 = fmaxf(e0, fabsf(((j4N*4+1==iN)?1.f:0.f) - acc.y));
                e0 = fmaxf(e0, fabsf(((j4N*4+2==iN)?1.f:0.f) - acc.z));
                e0 = fmaxf(e0, fabsf(((j4N*4+3==iN)?1.f:0.f) - acc.w));
                #pragma unroll
                for (int off = 32; off; off >>= 1) e0 = fmaxf(e0, __shfl_xor(e0, off, 64));
                if ((tid & 63) == 0) atomicMax(&red_a, __float_as_int(e0));
            }
            __syncthreads();
            float resid = __int_as_float(red_a);           // uniform
            if (resid < NEWTON_TOL) break;
            bool bad = !(resid < 1e30f);
            if ((bad || resid > 0.9f) && restarted == 0) { // rescue re-init
                if (tid == 0) red_a = 0;
                __syncthreads();
                if (tid < 256) {
                    float rs = 0.f;
                    #pragma unroll
                    for (int c = 0; c < 4; ++c) rs += fabsf(Smp[iN*36 + j4N*4 + c]);
                    rs += __shfl_xor(rs, 1, 64);
                    rs += __shfl_xor(rs, 2, 64);
                    rs += __shfl_xor(rs, 4, 64);
                    if ((tid & 7) == 0) atomicMax(&red_a, __float_as_int(rs));
                }
                __syncthreads();
                float inv = 1.0f / __int_as_float(red_a);
                if (tid < 256) {
                    f4 y;
                    y.x = (j4N*4+0 == iN) ? inv : 0.f;
                    y.y = (j4N*4+1 == iN) ? inv : 0.f;
                    y.z = (j4N*4+2 == iN) ? inv : 0.f;
                    y.w = (j4N*4+3 == iN) ? inv : 0.f;
                    Ycur4[iN*9 + j4N] = y;
                }
                if (tid == 0) { restarted = 1; red_a = 0; }
                __syncthreads();
                continue;
            }
            if (tid < 256) {
                f4 up = 2.f * Ycur4[iN*9 + j4N];
                #pragma unroll
                for (int k4 = 0; k4 < 8; ++k4) {
                    f4 a  = Ycur4[iN*9 + k4];
                    f4 b0 = T1p4[(k4*4+0)*9 + j4N];
                    f4 b1 = T1p4[(k4*4+1)*9 + j4N];
                    f4 b2 = T1p4[(k4*4+2)*9 + j4N];
                    f4 b3 = T1p4[(k4*4+3)*9 + j4N];
                    up -= a.x*b0 + a.y*b1 + a.z*b2 + a.w*b3;
                }
                Yalt4[iN*9 + j4N] = up;
            }
            if (tid == 0) red_a = 0;
            __syncthreads();
            f4* tmp = Ycur4; Ycur4 = Yalt4; Yalt4 = tmp;   // uniform swap
        }

        // --- d: K' = Y * HP  ->  KT36[s][m] = K'[m][s]  (2-row, 256 threads)
        if (tid < 256) {
            f4 a0={0,0,0,0}, a1={0,0,0,0};
            #pragma unroll
            for (int n4 = 0; n4 < 8; ++n4) {
                f4 b0 = HPp4[(n4*4+0)*17 + j4f];
                f4 b1 = HPp4[(n4*4+1)*17 + j4f];
                f4 b2 = HPp4[(n4*4+2)*17 + j4f];
                f4 b3 = HPp4[(n4*4+3)*17 + j4f];
                f4 ya;
                ya = Ycur4[(mg    )*9 + n4]; a0 += ya.x*b0 + ya.y*b1 + ya.z*b2 + ya.w*b3;
                ya = Ycur4[(mg+16)*9 + n4]; a1 += ya.x*b0 + ya.y*b1 + ya.z*b2 + ya.w*b3;
            }
            #pragma unroll
            for (int c = 0; c < 4; ++c) {
                KT36[(j4f*4+c)*36 + mg     ] = a0[c];
                KT36[(j4f*4+c)*36 + mg + 16] = a1[c];
            }
        }
        __syncthreads();

        // --- store K^T[t] to global, [s][m4] f4 coalesced (512 threads = 512 f4)
        {
            int s = tid >> 3, m4 = tid & 7;
            f4 v = { KT36[s*36 + m4*4 + 0], KT36[s*36 + m4*4 + 1],
                     KT36[s*36 + m4*4 + 2], KT36[s*36 + m4*4 + 3] };
            KT_g4[(size_t)t*512 + tid] = v;
        }

        if (t == T_EXACT - 1) {
            // --- emit closed-loop A = F - FK*H, G = FK (FK = F*K'^T)
            for (int idx = tid; idx < 64*32; idx += 512) {
                int l = idx >> 5, m = idx & 31;
                float acc = 0.f;
                #pragma unroll 8
                for (int s = 0; s < 64; ++s) acc += Ff[l*68 + s] * KT36[s*36 + m];
                Gs[l*33 + m] = acc;
            }
            __syncthreads();
            for (int idx = tid; idx < 1024; idx += 512) {
                int j4 = idx >> 6, l = idx & 63;
                f4 aa;
                #pragma unroll
                for (int c = 0; c < 4; ++c) {
                    int j = j4*4 + c;
                    float a = Ff[l*68 + j];
                    #pragma unroll 8
                    for (int m = 0; m < 32; ++m) a -= Gs[l*33 + m] * Hp[m*68 + j];
                    aa[c] = a;
                }
                AT_g4[j4*64 + l] = aa;
            }
            {
                int m4 = tid >> 6, l = tid & 63;   // 512 threads = 8 x 64
                f4 gg = { Gs[l*33 + m4*4 + 0], Gs[l*33 + m4*4 + 1],
                          Gs[l*33 + m4*4 + 2], Gs[l*33 + m4*4 + 3] };
                GT_g4[m4*64 + l] = gg;
            }
            break;
        }

        // --- e: P -= K'^T * HP (own element, 2-row: rg, rg+32)
        {
            f4 a0 = Ps4[(rg    )*16 + j4f];
            f4 a1 = Ps4[(rg+32)*16 + j4f];
            #pragma unroll
            for (int m4 = 0; m4 < 8; ++m4) {
                f4 b0 = HPp4[(m4*4+0)*17 + j4f];
                f4 b1 = HPp4[(m4*4+1)*17 + j4f];
                f4 b2 = HPp4[(m4*4+2)*17 + j4f];
                f4 b3 = HPp4[(m4*4+3)*17 + j4f];
                f4 ka;
                ka = KT364[(rg    )*9 + m4]; a0 -= ka.x*b0 + ka.y*b1 + ka.z*b2 + ka.w*b3;
                ka = KT364[(rg+32)*9 + m4]; a1 -= ka.x*b0 + ka.y*b1 + ka.z*b2 + ka.w*b3;
            }
            Ps4[(rg    )*16 + j4f] = a0;
            Ps4[(rg+32)*16 + j4f] = a1;
        }
        __syncthreads();

        PH_F(); __syncthreads();
        PH_G(); __syncthreads();
    }
}

// ---------------------------------------------------------------------------
// Kernel 2: per-batch state recursion, one wave per batch (256 blocks x 64)
// ---------------------------------------------------------------------------
__global__ __launch_bounds__(64)
void filter_kernel(const float* __restrict__ obs, const float* __restrict__ F,
                   const float* __restrict__ H, const float* __restrict__ x0,
                   const float* __restrict__ K_T, const float* __restrict__ AT_g,
                   const float* __restrict__ GT_g, float* __restrict__ out)
{
    const int lane = threadIdx.x;
    const int b    = blockIdx.x;
    const int m    = lane & 31;

    __shared__ __align__(16) float xb[64];
    __shared__ __align__(16) float rb[32];
    __shared__ __align__(16) float ub[64];
    const f4* xb4 = (const f4*)xb;
    const f4* rb4 = (const f4*)rb;
    const f4* ub4 = (const f4*)ub;

    f4 Fr4[16], Hr4[16];
    #pragma unroll
    for (int k = 0; k < 16; ++k) Fr4[k] = ((const f4*)(F + lane*64))[k];
    #pragma unroll
    for (int k = 0; k < 16; ++k) Hr4[k] = ((const f4*)(H + m*64))[k];

    float x;
    {   // x = F x0 (initial predict)
        f4 a = {0.f,0.f,0.f,0.f};
        #pragma unroll
        for (int k = 0; k < 16; ++k) a += Fr4[k] * ((const f4*)x0)[k];
        x = (a[0]+a[1]) + (a[2]+a[3]);
    }

    const float* obs_b = obs + (size_t)b * (Tdim*Mdim);
    float*       out_b = out + (size_t)b * (Tdim*Mdim);
    float o0 = obs_b[m];
    float o1 = obs_b[Mdim + m];

    const f4* KT4 = (const f4*)K_T;

    // ---- exact phase: t in [0, T_EXACT)
    for (int t = 0; t < T_EXACT; ++t) {
        f4 ku[8];                               // lane's K^T row (128B coalesced)
        #pragma unroll
        for (int k = 0; k < 8; ++k) ku[k] = KT4[(size_t)t*512 + lane*8 + k];

        xb[lane] = x;
        asm volatile("s_waitcnt lgkmcnt(0)" ::: "memory");
        f4 za = {0.f,0.f,0.f,0.f};
        #pragma unroll
        for (int k = 0; k < 16; ++k) za += Hr4[k] * xb4[k];
        float z = (za[0]+za[1]) + (za[2]+za[3]);
        if (lane < 32) { out_b[t*Mdim + lane] = z; rb[lane] = o0 - z; }
        o0 = o1;
        if (t + 2 < Tdim) o1 = obs_b[(t+2)*Mdim + m];
        asm volatile("s_waitcnt lgkmcnt(0)" ::: "memory");
        f4 ua = {0.f,0.f,0.f,0.f};
        #pragma unroll
        for (int k = 0; k < 8; ++k) ua += ku[k] * rb4[k];
        float u = x + (ua[0]+ua[1]) + (ua[2]+ua[3]);
        ub[lane] = u;
        asm volatile("s_waitcnt lgkmcnt(0)" ::: "memory");
        f4 xa = {0.f,0.f,0.f,0.f};
        #pragma unroll
        for (int k = 0; k < 16; ++k) xa += Fr4[k] * ub4[k];
        x = (xa[0]+xa[1]) + (xa[2]+xa[3]);
    }

    // ---- frozen phase: x <- A x + G o, A/G rows in VGPRs
    {
        f4 Ar[16], Gr[8];
        #pragma unroll
        for (int k = 0; k < 16; ++k) Ar[k] = ((const f4*)AT_g)[k*64 + lane];
        #pragma unroll
        for (int k = 0; k < 8; ++k)  Gr[k] = ((const f4*)GT_g)[k*64 + lane];

        for (int t = T_EXACT; t < Tdim; ++t) {
            xb[lane] = x;
            if (lane < 32) rb[lane] = o0;
            asm volatile("s_waitcnt lgkmcnt(0)" ::: "memory");
            f4 za = {0.f,0.f,0.f,0.f}, xa = {0.f,0.f,0.f,0.f};
            #pragma unroll
            for (int k = 0; k < 16; ++k) {
                f4 xv = xb4[k];
                za += Hr4[k] * xv;
                xa += Ar[k] * xv;
            }
            #pragma unroll
            for (int k = 0; k < 8; ++k) xa += Gr[k] * rb4[k];
            float z = (za[0]+za[1]) + (za[2]+za[3]);
            if (lane < 32) out_b[t*Mdim + lane] = z;
            o0 = o1;
            if (t + 2 < Tdim) o1 = obs_b[(t+2)*Mdim + m];
            x = (xa[0]+xa[1]) + (xa[2]+xa[3]);
        }
    }
}

// ---------------------------------------------------------------------------
extern "C" void kernel_launch(void* const* d_in, const int* in_sizes, int n_in,
                              void* d_out, int out_size, void* d_ws, size_t ws_size,
                              hipStream_t stream)
{
    const float* obs = (const float*)d_in[0];
    const float* F   = (const float*)d_in[1];
    const float* H   = (const float*)d_in[2];
    const float* Q   = (const float*)d_in[3];
    const float* R   = (const float*)d_in[4];
    const float* x0  = (const float*)d_in[5];
    const float* P0  = (const float*)d_in[6];
    float* out = (float*)d_out;

    // ws: K_T (48*64*32 f32 = 384 KB) | AT (16 KB) @ +2 MiB | GT (8 KB)
    float* K_T  = (float*)d_ws;
    float* AT_g = (float*)((char*)d_ws + (2u << 20));
    float* GT_g = (float*)((char*)d_ws + (2u << 20) + 64*64*sizeof(float));

    hipLaunchKernelGGL(riccati_kernel, dim3(1), dim3(512), 0, stream,
                       F, H, Q, R, P0, K_T, AT_g, GT_g);
    hipLaunchKernelGGL(filter_kernel, dim3(256), dim3(64), 0, stream,
                       obs, F, H, x0, K_T, AT_g, GT_g, out);
}